// Round 22
// baseline (960.465 us; speedup 1.0000x reference)
//
#include <hip/hip_runtime.h>
#include <type_traits>
#include <stdint.h>

#define NN 4096
#define TTOT 16777216UL

enum { F_RELU=1, F_ACC=2, F_RS=4, F_BIAS=8 };

typedef unsigned short ushort_t;
using bf16x8 = __attribute__((ext_vector_type(8))) short;
using f32x4  = __attribute__((ext_vector_type(4))) float;

struct SelParams {
  unsigned min_ord, max_ord, n_up;
  float lo, M, c0;
  unsigned n_change, rm_prefix, rm_k, add_prefix, add_k;
  float t_rm, t_add;
  unsigned hist_rm[256], hist_add[256];
};

__device__ __forceinline__ unsigned ordenc(float x){
  unsigned u = __float_as_uint(x);
  return (u & 0x80000000u) ? ~u : (u | 0x80000000u);
}
__device__ __forceinline__ float orddec_ok(unsigned o){
  unsigned u = (o & 0x80000000u) ? (o ^ 0x80000000u) : ~o;
  return __uint_as_float(u);
}
__device__ __forceinline__ ushort_t f2bf(float x){
  unsigned u = __float_as_uint(x);
  return (ushort_t)((u + 0x7FFFu + ((u >> 16) & 1u)) >> 16);
}
__device__ __forceinline__ float bf2f(ushort_t h){
  return __uint_as_float(((unsigned)h) << 16);
}

// ---------------- B -> 3 exact bf16 planes, transposed (r19 verbatim) ------
template<int DN>
__global__ __launch_bounds__(256)
void k_b3t(const float* __restrict__ Bsrc, ushort_t* __restrict__ H,
           ushort_t* __restrict__ Mg, ushort_t* __restrict__ L)
{
  __shared__ ushort_t sh[64][65], sm[64][65], sl[64][65];
  const int t = threadIdx.x;
  const int n0 = blockIdx.x * 64, k0 = blockIdx.y * 64;
  #pragma unroll
  for (int it = 0; it < 16; ++it){
    int idx = it*256 + t; int r = idx >> 6, c = idx & 63;
    float x  = Bsrc[(size_t)(k0 + r)*DN + n0 + c];
    ushort_t hb = f2bf(x);
    float r1 = x - bf2f(hb);
    ushort_t mb = f2bf(r1);
    float r2 = r1 - bf2f(mb);
    ushort_t lb = f2bf(r2);
    sh[r][c] = hb; sm[r][c] = mb; sl[r][c] = lb;
  }
  __syncthreads();
  #pragma unroll
  for (int it = 0; it < 16; ++it){
    int idx = it*256 + t; int r = idx >> 6, c = idx & 63;
    size_t o = (size_t)(n0 + r)*4096 + k0 + c;
    H[o] = sh[c][r]; Mg[o] = sm[c][r]; L[o] = sl[c][r];
  }
}

// ---------------- MFMA GEMM, split-K=2 (r19 verbatim) — used for P2 --------
__global__ __launch_bounds__(256)
void k_mfma(const signed char* __restrict__ A8,
            const ushort_t* __restrict__ BH, const ushort_t* __restrict__ BM2,
            const ushort_t* __restrict__ BL,
            float* __restrict__ C0, float* __restrict__ C1, int N)
{
  __shared__ ushort_t Ab[64][72];
  __shared__ ushort_t Bb[3][64][72];
  const int t = threadIdx.x;
  const int m0 = blockIdx.y * 64, n0 = blockIdx.x * 64;
  const int kz = blockIdx.z;
  const int kbase = kz * 2048;
  float* C = kz ? C1 : C0;
  const int sr = t >> 2, sc = (t & 3) * 16;
  const int w = t >> 6, lane = t & 63;
  const int fr = lane & 15, fg = lane >> 4;

  int4 a_r = *reinterpret_cast<const int4*>(A8 + (size_t)(m0+sr)*4096 + kbase + sc);
  const ushort_t* bsrc0 = BH  + (size_t)(n0+sr)*4096 + kbase + sc;
  const ushort_t* bsrc1 = BM2 + (size_t)(n0+sr)*4096 + kbase + sc;
  const ushort_t* bsrc2 = BL  + (size_t)(n0+sr)*4096 + kbase + sc;
  int4 b0a = reinterpret_cast<const int4*>(bsrc0)[0], b0b = reinterpret_cast<const int4*>(bsrc0)[1];
  int4 b1a = reinterpret_cast<const int4*>(bsrc1)[0], b1b = reinterpret_cast<const int4*>(bsrc1)[1];
  int4 b2a = reinterpret_cast<const int4*>(bsrc2)[0], b2b = reinterpret_cast<const int4*>(bsrc2)[1];

  f32x4 acc[4][3];
  #pragma unroll
  for (int c = 0; c < 4; ++c)
    #pragma unroll
    for (int p = 0; p < 3; ++p)
      acc[c][p] = (f32x4){0.f, 0.f, 0.f, 0.f};

  for (int k0 = 0; k0 < 2048; k0 += 64){
    {
      alignas(16) ushort_t tmp[16];
      const signed char* ab = reinterpret_cast<const signed char*>(&a_r);
      #pragma unroll
      for (int i = 0; i < 16; ++i) tmp[i] = f2bf((float)(int)ab[i]);  // exact
      *reinterpret_cast<int4*>(&Ab[sr][sc])     = reinterpret_cast<int4*>(tmp)[0];
      *reinterpret_cast<int4*>(&Ab[sr][sc + 8]) = reinterpret_cast<int4*>(tmp)[1];
      *reinterpret_cast<int4*>(&Bb[0][sr][sc])     = b0a;
      *reinterpret_cast<int4*>(&Bb[0][sr][sc + 8]) = b0b;
      *reinterpret_cast<int4*>(&Bb[1][sr][sc])     = b1a;
      *reinterpret_cast<int4*>(&Bb[1][sr][sc + 8]) = b1b;
      *reinterpret_cast<int4*>(&Bb[2][sr][sc])     = b2a;
      *reinterpret_cast<int4*>(&Bb[2][sr][sc + 8]) = b2b;
    }
    __syncthreads();
    if (k0 + 64 < 2048){
      a_r = *reinterpret_cast<const int4*>(A8 + (size_t)(m0+sr)*4096 + kbase + (k0+64) + sc);
      const ushort_t* p0 = BH  + (size_t)(n0+sr)*4096 + kbase + (k0+64) + sc;
      const ushort_t* p1 = BM2 + (size_t)(n0+sr)*4096 + kbase + (k0+64) + sc;
      const ushort_t* p2 = BL  + (size_t)(n0+sr)*4096 + kbase + (k0+64) + sc;
      b0a = reinterpret_cast<const int4*>(p0)[0]; b0b = reinterpret_cast<const int4*>(p0)[1];
      b1a = reinterpret_cast<const int4*>(p1)[0]; b1b = reinterpret_cast<const int4*>(p1)[1];
      b2a = reinterpret_cast<const int4*>(p2)[0]; b2b = reinterpret_cast<const int4*>(p2)[1];
    }
    #pragma unroll
    for (int kk = 0; kk < 64; kk += 32){
      bf16x8 af = *reinterpret_cast<const bf16x8*>(&Ab[w*16 + fr][kk + fg*8]);
      #pragma unroll
      for (int c = 0; c < 4; ++c){
        const int bn = c*16 + fr;
        bf16x8 bh = *reinterpret_cast<const bf16x8*>(&Bb[0][bn][kk + fg*8]);
        acc[c][0] = __builtin_amdgcn_mfma_f32_16x16x32_bf16(af, bh, acc[c][0], 0, 0, 0);
        bf16x8 bm = *reinterpret_cast<const bf16x8*>(&Bb[1][bn][kk + fg*8]);
        acc[c][1] = __builtin_amdgcn_mfma_f32_16x16x32_bf16(af, bm, acc[c][1], 0, 0, 0);
        bf16x8 bl = *reinterpret_cast<const bf16x8*>(&Bb[2][bn][kk + fg*8]);
        acc[c][2] = __builtin_amdgcn_mfma_f32_16x16x32_bf16(af, bl, acc[c][2], 0, 0, 0);
      }
    }
    __syncthreads();
  }
  #pragma unroll
  for (int c = 0; c < 4; ++c){
    f32x4 s = acc[c][0] + acc[c][1];
    s = s + acc[c][2];
    #pragma unroll
    for (int r = 0; r < 4; ++r)
      C[(size_t)(m0 + w*16 + fg*4 + r)*N + n0 + c*16 + fr] = s[r];
  }
}

// ---------------- MFMA GEMM v3, wide-N reuse — used for P ------------------
// Block 64m x 128n; wave = 4 m-tiles x 2 n-tiles. Per kk: 4 A-reads + 6
// B-reads feed 24 MFMA (2.6x less LDS traffic than k_mfma). One accumulator
// per tile (planes interleaved per k) — reassociation of P only, which is
// downstream of the discrete selection (smooth propagation).
__global__ __launch_bounds__(256)
void k_mfmaW(const signed char* __restrict__ A8,
             const ushort_t* __restrict__ BH, const ushort_t* __restrict__ BM2,
             const ushort_t* __restrict__ BL,
             float* __restrict__ C0, float* __restrict__ C1, int N)
{
  __shared__ ushort_t Ab[64][72];
  __shared__ ushort_t Bb[3][128][72];
  const int t = threadIdx.x;
  const int m0 = blockIdx.y * 64, n0 = blockIdx.x * 128;
  const int kz = blockIdx.z;
  const int kbase = kz * 2048;
  float* C = kz ? C1 : C0;
  const int sr = t >> 2, sc = (t & 3) * 16;   // A staging: row, 16-int8 col
  const int br = t >> 1, bc = (t & 1) * 32;   // B staging: row, 32-ushort col
  const int w = t >> 6, lane = t & 63;
  const int fr = lane & 15, fg = lane >> 4;

  int4 a_r = *reinterpret_cast<const int4*>(A8 + (size_t)(m0+sr)*4096 + kbase + sc);
  int4 b_r0[4], b_r1[4], b_r2[4];
  {
    const ushort_t* bp0 = BH  + (size_t)(n0+br)*4096 + kbase + bc;
    const ushort_t* bp1 = BM2 + (size_t)(n0+br)*4096 + kbase + bc;
    const ushort_t* bp2 = BL  + (size_t)(n0+br)*4096 + kbase + bc;
    #pragma unroll
    for (int q = 0; q < 4; ++q){
      b_r0[q] = reinterpret_cast<const int4*>(bp0)[q];
      b_r1[q] = reinterpret_cast<const int4*>(bp1)[q];
      b_r2[q] = reinterpret_cast<const int4*>(bp2)[q];
    }
  }

  f32x4 acc[4][2];
  #pragma unroll
  for (int mt = 0; mt < 4; ++mt)
    #pragma unroll
    for (int c = 0; c < 2; ++c)
      acc[mt][c] = (f32x4){0.f, 0.f, 0.f, 0.f};

  for (int k0 = 0; k0 < 2048; k0 += 64){
    {
      alignas(16) ushort_t tmp[16];
      const signed char* ab = reinterpret_cast<const signed char*>(&a_r);
      #pragma unroll
      for (int i = 0; i < 16; ++i) tmp[i] = f2bf((float)(int)ab[i]);  // exact
      *reinterpret_cast<int4*>(&Ab[sr][sc])     = reinterpret_cast<int4*>(tmp)[0];
      *reinterpret_cast<int4*>(&Ab[sr][sc + 8]) = reinterpret_cast<int4*>(tmp)[1];
      #pragma unroll
      for (int q = 0; q < 4; ++q){
        *reinterpret_cast<int4*>(&Bb[0][br][bc + q*8]) = b_r0[q];
        *reinterpret_cast<int4*>(&Bb[1][br][bc + q*8]) = b_r1[q];
        *reinterpret_cast<int4*>(&Bb[2][br][bc + q*8]) = b_r2[q];
      }
    }
    __syncthreads();
    if (k0 + 64 < 2048){
      a_r = *reinterpret_cast<const int4*>(A8 + (size_t)(m0+sr)*4096 + kbase + (k0+64) + sc);
      const ushort_t* bp0 = BH  + (size_t)(n0+br)*4096 + kbase + (k0+64) + bc;
      const ushort_t* bp1 = BM2 + (size_t)(n0+br)*4096 + kbase + (k0+64) + bc;
      const ushort_t* bp2 = BL  + (size_t)(n0+br)*4096 + kbase + (k0+64) + bc;
      #pragma unroll
      for (int q = 0; q < 4; ++q){
        b_r0[q] = reinterpret_cast<const int4*>(bp0)[q];
        b_r1[q] = reinterpret_cast<const int4*>(bp1)[q];
        b_r2[q] = reinterpret_cast<const int4*>(bp2)[q];
      }
    }
    #pragma unroll
    for (int kk = 0; kk < 64; kk += 32){
      bf16x8 af[4];
      #pragma unroll
      for (int mt = 0; mt < 4; ++mt)
        af[mt] = *reinterpret_cast<const bf16x8*>(&Ab[mt*16 + fr][kk + fg*8]);
      #pragma unroll
      for (int c = 0; c < 2; ++c){
        const int bn = w*32 + c*16 + fr;
        bf16x8 bh = *reinterpret_cast<const bf16x8*>(&Bb[0][bn][kk + fg*8]);
        bf16x8 bm = *reinterpret_cast<const bf16x8*>(&Bb[1][bn][kk + fg*8]);
        bf16x8 bl = *reinterpret_cast<const bf16x8*>(&Bb[2][bn][kk + fg*8]);
        #pragma unroll
        for (int mt = 0; mt < 4; ++mt){
          acc[mt][c] = __builtin_amdgcn_mfma_f32_16x16x32_bf16(af[mt], bh, acc[mt][c], 0, 0, 0);
          acc[mt][c] = __builtin_amdgcn_mfma_f32_16x16x32_bf16(af[mt], bm, acc[mt][c], 0, 0, 0);
          acc[mt][c] = __builtin_amdgcn_mfma_f32_16x16x32_bf16(af[mt], bl, acc[mt][c], 0, 0, 0);
        }
      }
    }
    __syncthreads();
  }
  #pragma unroll
  for (int mt = 0; mt < 4; ++mt)
    #pragma unroll
    for (int c = 0; c < 2; ++c)
      #pragma unroll
      for (int r = 0; r < 4; ++r)
        C[(size_t)(m0 + mt*16 + fg*4 + r)*N + n0 + w*32 + c*16 + fr] = acc[mt][c][r];
}

// ---------------- 2-way split-K reduce (r19 verbatim) ----------------------
__global__ __launch_bounds__(256)
void k_add2(const float* __restrict__ A, const float* __restrict__ B,
            float* __restrict__ O, int n4)
{
  int i = blockIdx.x*256 + threadIdx.x;
  if (i < n4){
    float4 a = reinterpret_cast<const float4*>(A)[i];
    float4 b = reinterpret_cast<const float4*>(B)[i];
    reinterpret_cast<float4*>(O)[i] = make_float4(a.x+b.x, a.y+b.y, a.z+b.z, a.w+b.w);
  }
}

// ---------------- Z = noise * exp(relu(LP)) + relu(MP) (r19 f32) -----------
__global__ __launch_bounds__(256)
void k_z2(const float* __restrict__ MPLP, const float* __restrict__ noise,
          float* __restrict__ Z)
{
  int i = blockIdx.x*256 + threadIdx.x;
  int m = i >> 7, c = i & 127;
  float mp = fmaxf(MPLP[(size_t)m*256 + c], 0.0f);
  float lp = fmaxf(MPLP[(size_t)m*256 + 128 + c], 0.0f);
  Z[i] = noise[i]*expf(lp) + mp;
}

// ---------------- symmetric logits GEMM (r19 f32 verbatim) -----------------
__global__ __launch_bounds__(256)
void k_zzt(const float* __restrict__ Z, float* __restrict__ C)
{
  const int bx = blockIdx.x, by = blockIdx.y;
  if (by > bx) return;
  __shared__ float As[16][68];
  __shared__ float Bs[16][68];
  const int t = threadIdx.x, tx = t & 15, ty = t >> 4;
  const int m0 = by*64, n0 = bx*64;
  const int mA = t >> 2, kA = (t & 3) * 4;
  float acc[4][4] = {};
  for (int k0 = 0; k0 < 128; k0 += 16){
    float4 va = *reinterpret_cast<const float4*>(Z + (size_t)(m0+mA)*128 + k0 + kA);
    As[kA+0][mA]=va.x; As[kA+1][mA]=va.y; As[kA+2][mA]=va.z; As[kA+3][mA]=va.w;
    float4 vb = *reinterpret_cast<const float4*>(Z + (size_t)(n0+mA)*128 + k0 + kA);
    Bs[kA+0][mA]=vb.x; Bs[kA+1][mA]=vb.y; Bs[kA+2][mA]=vb.z; Bs[kA+3][mA]=vb.w;
    __syncthreads();
    #pragma unroll
    for (int kk = 0; kk < 16; ++kk) {
      float4 av = *reinterpret_cast<const float4*>(&As[kk][ty*4]);
      float4 bv = *reinterpret_cast<const float4*>(&Bs[kk][tx*4]);
      float a[4]={av.x,av.y,av.z,av.w};
      float b[4]={bv.x,bv.y,bv.z,bv.w};
      #pragma unroll
      for (int i=0;i<4;++i)
        #pragma unroll
        for (int j=0;j<4;++j)
          acc[i][j] = fmaf(a[i], b[j], acc[i][j]);
    }
    __syncthreads();
  }
  #pragma unroll
  for (int i=0;i<4;++i){
    float* cp = C + (size_t)(m0+ty*4+i)*NN + (n0 + tx*4);
    *reinterpret_cast<float4*>(cp) = make_float4(acc[i][0],acc[i][1],acc[i][2],acc[i][3]);
  }
  if (bx != by){
    for (int c0 = 0; c0 < 64; c0 += 16){
      __syncthreads();
      if (tx >= c0/4 && tx < c0/4 + 4){
        #pragma unroll
        for (int i=0;i<4;++i)
          #pragma unroll
          for (int j=0;j<4;++j)
            As[tx*4 + j - c0][ty*4 + i] = acc[i][j];
      }
      __syncthreads();
      const int c = t & 63, r0 = t >> 6;
      #pragma unroll
      for (int rr = 0; rr < 4; ++rr)
        C[(size_t)(n0 + c0 + r0 + rr*4)*NN + m0 + c] = As[r0 + rr*4][c];
    }
  }
}

// ---------------- M32xN64 tiled GEMM (r19 verbatim) ------------------------
template<typename TA>
__global__ __launch_bounds__(256)
void k_gemm32(const TA* __restrict__ A, const float* __restrict__ B,
              float* __restrict__ C, int M, int N, int K, int ldc,
              const float* __restrict__ rowscale, const float* __restrict__ bias,
              int flags)
{
  __shared__ float As[16][36];
  __shared__ float Bs[16][68];
  const int t  = threadIdx.x;
  const int tx = t & 15, ty = t >> 4;
  const int m0 = blockIdx.y * 32, n0 = blockIdx.x * 64;
  float acc[2][4] = {};
  for (int k0 = 0; k0 < K; k0 += 16) {
    if (t < 128){
      const int mA = t >> 2, kA = (t & 3) * 4;
      if constexpr (std::is_same<TA, float>::value) {
        float4 v = *reinterpret_cast<const float4*>(A + (size_t)(m0+mA)*K + (k0+kA));
        As[kA+0][mA]=v.x; As[kA+1][mA]=v.y; As[kA+2][mA]=v.z; As[kA+3][mA]=v.w;
      } else {
        int u = *reinterpret_cast<const int*>(A + (size_t)(m0+mA)*K + (k0+kA));
        As[kA+0][mA]=(float)(int)(signed char)( u       & 0xff);
        As[kA+1][mA]=(float)(int)(signed char)((u>>8)   & 0xff);
        As[kA+2][mA]=(float)(int)(signed char)((u>>16)  & 0xff);
        As[kA+3][mA]=(float)(int)(signed char)((u>>24)  & 0xff);
      }
    }
    {
      const int kB = t >> 4, nB = (t & 15) * 4;
      float4 w = *reinterpret_cast<const float4*>(B + (size_t)(k0+kB)*N + (n0+nB));
      Bs[kB][nB+0]=w.x; Bs[kB][nB+1]=w.y; Bs[kB][nB+2]=w.z; Bs[kB][nB+3]=w.w;
    }
    __syncthreads();
    #pragma unroll
    for (int kk = 0; kk < 16; ++kk) {
      float a0 = As[kk][ty*2+0];
      float a1 = As[kk][ty*2+1];
      float4 bv = *reinterpret_cast<const float4*>(&Bs[kk][tx*4]);
      float b[4]={bv.x,bv.y,bv.z,bv.w};
      #pragma unroll
      for (int j=0;j<4;++j){
        acc[0][j] = fmaf(a0, b[j], acc[0][j]);
        acc[1][j] = fmaf(a1, b[j], acc[1][j]);
      }
    }
    __syncthreads();
  }
  #pragma unroll
  for (int i=0;i<2;++i){
    const int m = m0 + ty*2 + i;
    const float rsv = (flags & F_RS) ? rowscale[m] : 1.0f;
    float* cp = C + (size_t)m*ldc + (n0 + tx*4);
    float o[4];
    #pragma unroll
    for (int j=0;j<4;++j){
      float v = acc[i][j] * rsv;
      if (flags & F_BIAS) v += bias[n0 + tx*4 + j];
      if (flags & F_ACC)  v += cp[j];
      if (flags & F_RELU) v = fmaxf(v, 0.0f);
      o[j] = v;
    }
    *reinterpret_cast<float4*>(cp) = make_float4(o[0],o[1],o[2],o[3]);
  }
}

// ---------------- M32 tiled GEMM, B transposed (r19 verbatim) --------------
__global__ __launch_bounds__(256)
void k_gemm32T(const float* __restrict__ A, const float* __restrict__ B,
               float* __restrict__ C, int M, int N, int K, int ldc)
{
  __shared__ float As[16][36];
  __shared__ float Bs[16][68];
  const int t  = threadIdx.x;
  const int tx = t & 15, ty = t >> 4;
  const int m0 = blockIdx.y * 32, n0 = blockIdx.x * 64;
  float acc[2][4] = {};
  for (int k0 = 0; k0 < K; k0 += 16) {
    if (t < 128){
      const int mA = t >> 2, kA = (t & 3) * 4;
      float4 v = *reinterpret_cast<const float4*>(A + (size_t)(m0+mA)*K + (k0+kA));
      As[kA+0][mA]=v.x; As[kA+1][mA]=v.y; As[kA+2][mA]=v.z; As[kA+3][mA]=v.w;
    }
    {
      const int nB = t >> 2, kB = (t & 3) * 4;
      float4 w = *reinterpret_cast<const float4*>(B + (size_t)(n0+nB)*K + (k0+kB));
      Bs[kB+0][nB]=w.x; Bs[kB+1][nB]=w.y; Bs[kB+2][nB]=w.z; Bs[kB+3][nB]=w.w;
    }
    __syncthreads();
    #pragma unroll
    for (int kk = 0; kk < 16; ++kk) {
      float a0 = As[kk][ty*2+0];
      float a1 = As[kk][ty*2+1];
      float4 bv = *reinterpret_cast<const float4*>(&Bs[kk][tx*4]);
      float b[4]={bv.x,bv.y,bv.z,bv.w};
      #pragma unroll
      for (int j=0;j<4;++j){
        acc[0][j] = fmaf(a0, b[j], acc[0][j]);
        acc[1][j] = fmaf(a1, b[j], acc[1][j]);
      }
    }
    __syncthreads();
  }
  #pragma unroll
  for (int i=0;i<2;++i){
    const int m = m0 + ty*2 + i;
    float* cp = C + (size_t)m*ldc + (n0 + tx*4);
    *reinterpret_cast<float4*>(cp) = make_float4(acc[i][0],acc[i][1],acc[i][2],acc[i][3]);
  }
}

// ---------------- fused dual GEMM (r19 verbatim) ---------------------------
__global__ __launch_bounds__(256)
void k_fc(const float* __restrict__ A1, const float* __restrict__ B1,
          const float* __restrict__ bias,
          const float* __restrict__ A2, const float* __restrict__ B2,
          const float* __restrict__ rowscale,
          float* __restrict__ C, int N, int K1, int K2, int relu)
{
  __shared__ float As[16][36];
  __shared__ float Bs[16][68];
  const int t  = threadIdx.x;
  const int tx = t & 15, ty = t >> 4;
  const int m0 = blockIdx.y * 32, n0 = blockIdx.x * 64;
  float acc1[2][4] = {};
  float acc2[2][4] = {};
  for (int k0 = 0; k0 < K1; k0 += 16) {
    if (t < 128){
      const int mA = t >> 2, kA = (t & 3) * 4;
      float4 v = *reinterpret_cast<const float4*>(A1 + (size_t)(m0+mA)*K1 + (k0+kA));
      As[kA+0][mA]=v.x; As[kA+1][mA]=v.y; As[kA+2][mA]=v.z; As[kA+3][mA]=v.w;
    }
    {
      const int kB = t >> 4, nB = (t & 15) * 4;
      float4 w = *reinterpret_cast<const float4*>(B1 + (size_t)(k0+kB)*N + (n0+nB));
      Bs[kB][nB+0]=w.x; Bs[kB][nB+1]=w.y; Bs[kB][nB+2]=w.z; Bs[kB][nB+3]=w.w;
    }
    __syncthreads();
    #pragma unroll
    for (int kk = 0; kk < 16; ++kk) {
      float a0 = As[kk][ty*2+0];
      float a1 = As[kk][ty*2+1];
      float4 bv = *reinterpret_cast<const float4*>(&Bs[kk][tx*4]);
      float b[4]={bv.x,bv.y,bv.z,bv.w};
      #pragma unroll
      for (int j=0;j<4;++j){
        acc1[0][j] = fmaf(a0, b[j], acc1[0][j]);
        acc1[1][j] = fmaf(a1, b[j], acc1[1][j]);
      }
    }
    __syncthreads();
  }
  for (int k0 = 0; k0 < K2; k0 += 16) {
    if (t < 128){
      const int mA = t >> 2, kA = (t & 3) * 4;
      float4 v = *reinterpret_cast<const float4*>(A2 + (size_t)(m0+mA)*K2 + (k0+kA));
      As[kA+0][mA]=v.x; As[kA+1][mA]=v.y; As[kA+2][mA]=v.z; As[kA+3][mA]=v.w;
    }
    {
      const int kB = t >> 4, nB = (t & 15) * 4;
      float4 w = *reinterpret_cast<const float4*>(B2 + (size_t)(k0+kB)*N + (n0+nB));
      Bs[kB][nB+0]=w.x; Bs[kB][nB+1]=w.y; Bs[kB][nB+2]=w.z; Bs[kB][nB+3]=w.w;
    }
    __syncthreads();
    #pragma unroll
    for (int kk = 0; kk < 16; ++kk) {
      float a0 = As[kk][ty*2+0];
      float a1 = As[kk][ty*2+1];
      float4 bv = *reinterpret_cast<const float4*>(&Bs[kk][tx*4]);
      float b[4]={bv.x,bv.y,bv.z,bv.w};
      #pragma unroll
      for (int j=0;j<4;++j){
        acc2[0][j] = fmaf(a0, b[j], acc2[0][j]);
        acc2[1][j] = fmaf(a1, b[j], acc2[1][j]);
      }
    }
    __syncthreads();
  }
  #pragma unroll
  for (int i=0;i<2;++i){
    const int m = m0 + ty*2 + i;
    const float rsv = rowscale[m];
    float* cp = C + (size_t)m*N + (n0 + tx*4);
    float o[4];
    #pragma unroll
    for (int j=0;j<4;++j){
      float t1 = acc1[i][j] + bias[n0 + tx*4 + j];
      float v  = acc2[i][j] * rsv;
      v += t1;
      if (relu) v = fmaxf(v, 0.0f);
      o[j] = v;
    }
    *reinterpret_cast<float4*>(cp) = make_float4(o[0],o[1],o[2],o[3]);
  }
}

// ---------------- weight concat (r19 verbatim) -----------------------------
__global__ __launch_bounds__(256)
void k_wcat(const float* __restrict__ Wm, const float* __restrict__ Wl,
            float* __restrict__ Wcat)
{
  int idx = blockIdx.x*256 + threadIdx.x;
  int row = idx >> 8, col = idx & 255;
  Wcat[idx] = (col < 128) ? Wm[row*128 + col] : Wl[row*128 + (col - 128)];
}

// ---------------- per-row compact-gather SpMM (r19 verbatim) ---------------
template<int D>
__global__ __launch_bounds__(256)
void k_spmmF(const float* __restrict__ A, const float* __restrict__ B,
             float* __restrict__ C)
{
  const int row = blockIdx.x, t = threadIdx.x;
  const int lane = t & 63, wv = t >> 6;
  __shared__ int   sc[288];
  __shared__ float sv[288];
  __shared__ int wtot[4];
  __shared__ int nsh;
  const float4* r4 = reinterpret_cast<const float4*>(A + (size_t)row*NN) + t*4;
  float lv[16];
  #pragma unroll
  for (int q=0;q<4;++q){
    float4 v = r4[q];
    lv[q*4+0]=v.x; lv[q*4+1]=v.y; lv[q*4+2]=v.z; lv[q*4+3]=v.w;
  }
  int c = 0;
  #pragma unroll
  for (int k=0;k<16;++k) c += (lv[k] != 0.0f);
  int inc = c;
  #pragma unroll
  for (int off=1; off<64; off<<=1){
    int v = __shfl_up(inc, off, 64);
    if (lane >= off) inc += v;
  }
  if (lane == 63) wtot[wv] = inc;
  __syncthreads();
  int wbase = 0;
  #pragma unroll
  for (int ww=0; ww<3; ++ww) if (ww < wv) wbase += wtot[ww];
  int pos = wbase + inc - c;
  #pragma unroll
  for (int k=0;k<16;++k){
    if (lv[k] != 0.0f){
      if (pos >= 0 && pos < 288){ sc[pos] = t*16+k; sv[pos] = lv[k]; }
      pos++;
    }
  }
  if (t == 255){
    int tot = wbase + inc;
    nsh = (tot < 288) ? tot : 288;
  }
  __syncthreads();
  const int n = nsh;
  float acc = 0.f;
  int s = 0;
  for (; s+4 <= n; s += 4){
    float x0 = B[(size_t)sc[s+0]*D + t];
    float x1 = B[(size_t)sc[s+1]*D + t];
    float x2 = B[(size_t)sc[s+2]*D + t];
    float x3 = B[(size_t)sc[s+3]*D + t];
    acc = fmaf(sv[s+0], x0, acc);
    acc = fmaf(sv[s+1], x1, acc);
    acc = fmaf(sv[s+2], x2, acc);
    acc = fmaf(sv[s+3], x3, acc);
  }
  for (; s < n; ++s) acc = fmaf(sv[s], B[(size_t)sc[s]*D + t], acc);
  C[(size_t)row*D + t] = acc;
}

// ---------------- selection (r19 verbatim) ---------------------------------
__global__ __launch_bounds__(256)
void k_initstats(SelParams* p)
{
  int t = threadIdx.x;
  if (t == 0){
    p->min_ord = 0xFFFFFFFFu; p->max_ord = 0u; p->n_up = 0u;
    p->rm_prefix = 0u; p->add_prefix = 0u;
  }
  p->hist_rm[t] = 0u; p->hist_add[t] = 0u;
}

__global__ __launch_bounds__(256)
void k_stats1(const float* __restrict__ L, const float* __restrict__ adj,
              unsigned long long* __restrict__ mask, SelParams* __restrict__ p)
{
  unsigned mn=0xFFFFFFFFu, mx=0u, cnt=0u;
  size_t g = (size_t)blockIdx.x*256 + threadIdx.x;
  const size_t stride = (size_t)gridDim.x*256;
  for (; g < 262144; g += stride){
    const int i  = (int)(g >> 6);
    const int jb = (int)(g & 63) << 6;
    unsigned long long m = 0ull;
    if (jb + 63 > i){
      const float4* a4 = reinterpret_cast<const float4*>(adj + (size_t)i*NN + jb);
      const float4* l4 = reinterpret_cast<const float4*>(L   + (size_t)i*NN + jb);
      for (int w = 0; w < 16; ++w){
        const int j0 = jb + w*4;
        if (j0 + 3 <= i) continue;
        float4 av = a4[w]; float4 lv = l4[w];
        float ae[4]={av.x,av.y,av.z,av.w};
        float le[4]={lv.x,lv.y,lv.z,lv.w};
        #pragma unroll
        for (int e=0;e<4;++e){
          const int jj = j0 + e;
          if (jj > i){
            if (ae[e] != 0.0f){ m |= 1ull << (jj & 63); cnt++; }
            unsigned o = ordenc(le[e]);
            mn = (o < mn) ? o : mn;
            mx = (o > mx) ? o : mx;
          }
        }
      }
    }
    mask[g] = m;
  }
  __shared__ unsigned smn[256], smx[256], sc[256];
  int t = threadIdx.x;
  smn[t]=mn; smx[t]=mx; sc[t]=cnt; __syncthreads();
  for (int s=128; s>0; s>>=1){
    if (t < s){
      smn[t] = (smn[t+s] < smn[t]) ? smn[t+s] : smn[t];
      smx[t] = (smx[t+s] > smx[t]) ? smx[t+s] : smx[t];
      sc[t] += sc[t+s];
    }
    __syncthreads();
  }
  if (t == 0){
    atomicMin(&p->min_ord, smn[0]);
    atomicMax(&p->max_ord, smx[0]);
    atomicAdd(&p->n_up, sc[0]);
  }
}

__global__ void k_stats2(SelParams* p)
{
  float mnv = orddec_ok(p->min_ord), mxv = orddec_ok(p->max_ord);
  float lo = fminf(mnv, 0.0f), hi = fmaxf(mxv, 0.0f);
  p->lo = lo;
  p->M  = hi - lo;
  p->c0 = (0.0f - lo) / p->M;
  p->n_change = p->n_up;
}

__global__ __launch_bounds__(256)
void k_hist2(const float* __restrict__ L, const unsigned long long* __restrict__ mask,
             SelParams* __restrict__ p, int shift)
{
  __shared__ unsigned hr[256], ha[256];
  const int t = threadIdx.x;
  hr[t]=0u; ha[t]=0u; __syncthreads();
  const float lo = p->lo, Mv = p->M;
  const unsigned pr = p->rm_prefix, pa = p->add_prefix;
  const float4* L4 = reinterpret_cast<const float4*>(L);
  size_t q = (size_t)blockIdx.x*256 + t;
  const size_t stride = (size_t)gridDim.x*256;
  for (; q < TTOT/4; q += stride){
    const int i = (int)(q >> 10);
    const int j = (int)(q & 1023) << 2;
    if (j + 3 <= i) continue;
    float4 l = L4[q];
    const unsigned long long w = mask[q >> 4];
    float le[4]={l.x,l.y,l.z,l.w};
    #pragma unroll
    for (int e=0;e<4;++e){
      const int jj = j + e;
      if (jj <= i) continue;
      const unsigned key = __float_as_uint((le[e] - lo) / Mv);
      if (key == 0u) continue;
      const bool edge = (w >> (jj & 63)) & 1ull;
      if (edge){
        if (shift == 24 || (key >> (shift+8)) == pr) atomicAdd(&hr[(key>>shift)&255u], 1u);
      } else {
        if (shift == 24 || (key >> (shift+8)) == pa) atomicAdd(&ha[(key>>shift)&255u], 1u);
      }
    }
  }
  __syncthreads();
  if (hr[t]) atomicAdd(&p->hist_rm[t], hr[t]);
  if (ha[t]) atomicAdd(&p->hist_add[t], ha[t]);
}

__global__ __launch_bounds__(256)
void k_scan2(SelParams* __restrict__ p, int shift)
{
  const int t = threadIdx.x;
  if (t == 0){
    const unsigned c0k  = __float_as_uint(p->c0);
    const unsigned n_up = p->n_up;
    {
      unsigned injb = 300u, inj = 0u;
      if (c0k != 0u && (shift == 24 || (c0k >> (shift+8)) == p->rm_prefix)){
        injb = (c0k >> shift) & 255u; inj = n_up;
      }
      unsigned k;
      if (shift == 24){
        unsigned tot = inj;
        for (int d=0; d<256; ++d) tot += p->hist_rm[d];
        k = (tot < p->n_change) ? tot : p->n_change;
      } else k = p->rm_k;
      unsigned cum = 0u, digit = 255u;
      for (int d=0; d<256; ++d){
        unsigned hd = p->hist_rm[d] + (((unsigned)d == injb) ? inj : 0u);
        if (cum + hd >= k){ digit = (unsigned)d; k -= cum; break; }
        cum += hd;
      }
      p->rm_prefix = (p->rm_prefix << 8) | digit;
      p->rm_k = k;
      if (shift == 0) p->t_rm = __uint_as_float(p->rm_prefix);
    }
    {
      unsigned injb = 300u, inj = 0u;
      if (c0k != 0u && (shift == 24 || (c0k >> (shift+8)) == p->add_prefix)){
        injb = (c0k >> shift) & 255u;
        inj  = 8386560u - n_up + 4096u;
      }
      unsigned k;
      if (shift == 24){
        unsigned tot = inj;
        for (int d=0; d<256; ++d) tot += p->hist_add[d];
        k = (tot < p->n_change) ? tot : p->n_change;
      } else k = p->add_k;
      unsigned cum = 0u, digit = 0u;
      for (int d=255; d>=0; --d){
        unsigned hd = p->hist_add[d] + (((unsigned)d == injb) ? inj : 0u);
        if (cum + hd >= k){ digit = (unsigned)d; k -= cum; break; }
        cum += hd;
      }
      p->add_prefix = (p->add_prefix << 8) | digit;
      p->add_k = k;
      if (shift == 0) p->t_add = __uint_as_float(p->add_prefix);
    }
  }
  __syncthreads();
  p->hist_rm[t] = 0u; p->hist_add[t] = 0u;
}

// ---------------- build adj_new (r19 verbatim) -----------------------------
__device__ __forceinline__ int adjval(bool edge, float v, float c0v, float trm, float tad)
{
  int rmU = (edge && v   >  0.0f && v   <= trm) ? 1 : 0;
  int rmL = (edge && c0v >  0.0f && c0v <= trm) ? 1 : 0;
  int adU = (!edge && v   >= tad) ? 1 : 0;
  int adL = (!edge && c0v >= tad) ? 1 : 0;
  return (edge ? 1 : 0) - rmU - rmL + adU + adL;
}

__global__ __launch_bounds__(256)
void k_apply(const float* __restrict__ L, const unsigned long long* __restrict__ mask,
             const SelParams* __restrict__ p, signed char* __restrict__ A8)
{
  const int bx = blockIdx.x, by = blockIdx.y;
  if (by > bx) return;
  const float lo=p->lo, Mv=p->M, c0v=p->c0, trm=p->t_rm, tad=p->t_add;
  const int i0 = by*64, j0 = bx*64, t = threadIdx.x;
  __shared__ signed char Vs[64][65];
  if (bx == by){
    for (int it=0; it<16; ++it){
      int e = it*256 + t; int r = e>>6, c = e&63;
      size_t idx = (size_t)(i0+r)*NN + (j0+c);
      if (r < c){
        bool edge = (mask[idx>>6] >> ((j0+c) & 63)) & 1ull;
        float v = (L[idx] - lo) / Mv;
        int val = adjval(edge, v, c0v, trm, tad);
        A8[idx] = (signed char)val;
        Vs[c][r] = (signed char)val;
      } else if (r == c){
        A8[idx] = 1;
      }
    }
    __syncthreads();
    for (int it=0; it<16; ++it){
      int e = it*256 + t; int r = e>>6, c = e&63;
      if (r > c) A8[(size_t)(i0+r)*NN + (j0+c)] = Vs[r][c];
    }
  } else {
    for (int it=0; it<16; ++it){
      int e = it*256 + t; int r = e>>6, c = e&63;
      size_t idx = (size_t)(i0+r)*NN + (j0+c);
      bool edge = (mask[idx>>6] >> ((j0+c) & 63)) & 1ull;
      float v = (L[idx] - lo) / Mv;
      int val = adjval(edge, v, c0v, trm, tad);
      A8[idx] = (signed char)val;
      Vs[c][r] = (signed char)val;
    }
    __syncthreads();
    for (int it=0; it<16; ++it){
      int e = it*256 + t; int r = e>>6, c = e&63;
      A8[(size_t)(j0+r)*NN + (i0+c)] = Vs[r][c];
    }
  }
}

// ---------------- per-row scale for mean_neigh (r19 verbatim) --------------
__global__ __launch_bounds__(256)
void k_rowsum8(const signed char* __restrict__ A8, float* __restrict__ s_mean)
{
  const int row = blockIdx.x, t = threadIdx.x;
  const int4 w = reinterpret_cast<const int4*>(A8 + (size_t)row*NN)[t];
  int s = 0, a = 0;
  int vs[4] = {w.x, w.y, w.z, w.w};
  #pragma unroll
  for (int q=0; q<4; ++q){
    int u = vs[q];
    #pragma unroll
    for (int b=0; b<4; ++b){
      int c = (int)(signed char)((u >> (8*b)) & 0xff);
      s += c; a += (c < 0) ? -c : c;
    }
  }
  __shared__ int rs_[256], ra_[256];
  rs_[t]=s; ra_[t]=a; __syncthreads();
  for (int st=128; st>0; st>>=1){
    if (t < st){ rs_[t]+=rs_[t+st]; ra_[t]+=ra_[t+st]; }
    __syncthreads();
  }
  if (t == 0){
    float rs = (float)rs_[0], ra = (float)ra_[0];
    float A = fmaxf(ra, 1e-12f);
    s_mean[row] = (1.0f / A) / (rs / A + 1e-7f);
  }
}

// ---------------- row log_softmax (r19 verbatim) ---------------------------
__global__ __launch_bounds__(256)
void k_lsm(float* __restrict__ X)
{
  const int row = blockIdx.x, t = threadIdx.x;
  float* x = X + (size_t)row*512;
  float v0 = x[t], v1 = x[t+256];
  __shared__ float red[256];
  red[t] = fmaxf(v0, v1); __syncthreads();
  for (int s=128; s>0; s>>=1){
    if (t < s) red[t] = fmaxf(red[t], red[t+s]);
    __syncthreads();
  }
  float m = red[0]; __syncthreads();
  red[t] = expf(v0-m) + expf(v1-m); __syncthreads();
  for (int s=128; s>0; s>>=1){
    if (t < s) red[t] += red[t+s];
    __syncthreads();
  }
  float ls = logf(red[0]);
  x[t]     = (v0 - m) - ls;
  x[t+256] = (v1 - m) - ls;
}

// ---------------- driver ---------------------------------------------------
extern "C" void kernel_launch(void* const* d_in, const int* in_sizes, int n_in,
                              void* d_out, int out_size, void* d_ws, size_t ws_size,
                              hipStream_t stream)
{
  (void)in_sizes; (void)n_in; (void)out_size; (void)ws_size;
  const float* adj_norm = (const float*)d_in[0];
  const float* adj_ori  = (const float*)d_in[1];
  const float* feats    = (const float*)d_in[2];
  const float* img      = (const float*)d_in[3];
  const float* csd_img  = (const float*)d_in[5];
  const float* noise    = (const float*)d_in[6];
  const float* Wb       = (const float*)d_in[7];
  const float* Wm       = (const float*)d_in[8];
  const float* Wl       = (const float*)d_in[9];
  const float* fc1W     = (const float*)d_in[10];
  const float* fc1b     = (const float*)d_in[11];
  const float* fc2W     = (const float*)d_in[12];
  const float* fc2b     = (const float*)d_in[13];

  float* out    = (float*)d_out;
  float* out_pt = out;                 // preds_total 4096x64
  float* out_ft = out + 262144;        // feat_total  4096x512 (free until fc2)
  float* out_pi = out + 2359296;       // preds_img   4096x64
  float* out_lg = out + 2621440;       // adj_logits  4096x4096

  char* W = (char*)d_ws;
  signed char* adj8 = (signed char*)W;                              // 16MB
  float* bufA   = (float*)(W + (16u<<20));                          // 8MB
  float* bufB   = (float*)(W + (24u<<20));                          // 4MB
  float* HMHL   = (float*)(W + (28u<<20));                          // 4MB
  float* MPLP   = (float*)(W + (32u<<20));                          // 4MB
  float* Z      = (float*)(W + (36u<<20));                          // 2MB
  unsigned long long* mask = (unsigned long long*)(W + (38u<<20));  // 2MB
  float* p2q0   = (float*)(W + (40u<<20));                          // 4MB
  float* s_mean = (float*)(W + (44u<<20));                          // 16KB
  SelParams* sp = (SelParams*)(W + (44u<<20) + 65536);
  float* Wcat   = (float*)(W + (45u<<20));                          // 256KB
  // B bf16 plane regions (dead buffers after apply):
  ushort_t* BT1h = (ushort_t*)(W + (28u<<20));   // 4MB
  ushort_t* BT1m = (ushort_t*)(W + (32u<<20));   // 4MB
  ushort_t* BT1l = (ushort_t*)(W + (36u<<20));   // 4MB (Z+mask region, dead after apply)
  ushort_t* BT2h = (ushort_t*)(W + (28u<<20));   // 2MB
  ushort_t* BT2m = (ushort_t*)(W + (30u<<20));   // 2MB
  ushort_t* BT2l = (ushort_t*)(W + (32u<<20));   // 2MB

  dim3 B(256);
  auto G32 = [](int M, int N){ return dim3((unsigned)(N/64), (unsigned)(M/32)); };

  // ---- ep_net ----
  k_gemm32<float><<<G32(4096,256),B,0,stream>>>(img, Wb, bufA, 4096,256,512,256, nullptr,nullptr,0);  // T1
  k_spmmF<256><<<4096,B,0,stream>>>(adj_norm, bufA, bufB);                                            // hidden
  k_wcat<<<256,B,0,stream>>>(Wm, Wl, Wcat);
  k_gemm32<float><<<G32(4096,256),B,0,stream>>>(bufB, Wcat, HMHL, 4096,256,256,256, nullptr,nullptr,0); // [HM|HL]
  k_spmmF<256><<<4096,B,0,stream>>>(adj_norm, HMHL, MPLP);                                            // [MP|LP]
  k_z2<<<2048,B,0,stream>>>(MPLP, noise, Z);
  k_zzt<<<dim3(64,64),B,0,stream>>>(Z, out_lg);                                                       // logits (f32)

  // ---- edge rewiring ----
  k_initstats<<<1,B,0,stream>>>(sp);
  k_stats1<<<1024,B,0,stream>>>(out_lg, adj_ori, mask, sp);
  k_stats2<<<1,1,0,stream>>>(sp);
  for (int shift = 24; shift >= 0; shift -= 8){
    k_hist2<<<2048,B,0,stream>>>(out_lg, mask, sp, shift);
    k_scan2<<<1,B,0,stream>>>(sp, shift);
  }
  k_apply<<<dim3(64,64),B,0,stream>>>(out_lg, mask, sp, adj8);

  // ---- row scales ----
  k_rowsum8<<<4096,B,0,stream>>>(adj8, s_mean);

  // ---- nc_net ----
  k_b3t<512><<<dim3(8,64),B,0,stream>>>(feats, BT1h, BT1m, BT1l);
  k_mfmaW<<<dim3(4,64,2),B,0,stream>>>(adj8, BT1h, BT1m, BT1l, bufA, out_ft, 512); // P halves (wide-N)
  k_add2<<<2048,B,0,stream>>>(bufA, out_ft, bufA, 524288);                         // P
  k_fc<<<G32(4096,256),B,0,stream>>>(feats, fc1W, fc1b, bufA, fc1W + 512*256, s_mean,
                                     bufB, 256, 512, 512, 1);                      // h1
  k_b3t<256><<<dim3(4,64),B,0,stream>>>(bufB, BT2h, BT2m, BT2l);
  k_mfma<<<dim3(4,64,2),B,0,stream>>>(adj8, BT2h, BT2m, BT2l, p2q0, out_ft, 256);  // P2 halves
  k_add2<<<1024,B,0,stream>>>(p2q0, out_ft, bufA, 262144);                         // P2
  k_fc<<<G32(4096,512),B,0,stream>>>(bufB, fc2W, fc2b, bufA, fc2W + 256*512, s_mean,
                                     out_ft, 512, 256, 256, 0);
  k_lsm<<<4096,B,0,stream>>>(out_ft);

  // ---- heads ----
  k_gemm32T<<<G32(4096,64),B,0,stream>>>(out_ft, csd_img, out_pt, 4096,64,512,64);
  k_gemm32T<<<G32(4096,64),B,0,stream>>>(img, csd_img, out_pi, 4096,64,512,64);
}

// Round 23
// 844.887 us; speedup vs baseline: 1.1368x; 1.1368x over previous
//
#include <hip/hip_runtime.h>
#include <type_traits>
#include <stdint.h>

#define NN 4096
#define TTOT 16777216UL

enum { F_RELU=1, F_ACC=2, F_RS=4, F_BIAS=8 };

typedef unsigned short ushort_t;
using bf16x8 = __attribute__((ext_vector_type(8))) short;
using f32x4  = __attribute__((ext_vector_type(4))) float;

struct SelParams {
  unsigned min_ord, max_ord, n_up;
  float lo, M, c0;
  unsigned n_change, rm_prefix, rm_k, add_prefix, add_k;
  float t_rm, t_add;
  unsigned hist_rm[256], hist_add[256];
};

__device__ __forceinline__ unsigned ordenc(float x){
  unsigned u = __float_as_uint(x);
  return (u & 0x80000000u) ? ~u : (u | 0x80000000u);
}
__device__ __forceinline__ float orddec_ok(unsigned o){
  unsigned u = (o & 0x80000000u) ? (o ^ 0x80000000u) : ~o;
  return __uint_as_float(u);
}
__device__ __forceinline__ ushort_t f2bf(float x){
  unsigned u = __float_as_uint(x);
  return (ushort_t)((u + 0x7FFFu + ((u >> 16) & 1u)) >> 16);
}
__device__ __forceinline__ float bf2f(ushort_t h){
  return __uint_as_float(((unsigned)h) << 16);
}

// ---------------- B -> 3 exact bf16 planes, transposed ---------------------
template<int DN>
__global__ __launch_bounds__(256)
void k_b3t(const float* __restrict__ Bsrc, ushort_t* __restrict__ H,
           ushort_t* __restrict__ Mg, ushort_t* __restrict__ L)
{
  __shared__ ushort_t sh[64][65], sm[64][65], sl[64][65];
  const int t = threadIdx.x;
  const int n0 = blockIdx.x * 64, k0 = blockIdx.y * 64;
  #pragma unroll
  for (int it = 0; it < 16; ++it){
    int idx = it*256 + t; int r = idx >> 6, c = idx & 63;
    float x  = Bsrc[(size_t)(k0 + r)*DN + n0 + c];
    ushort_t hb = f2bf(x);
    float r1 = x - bf2f(hb);
    ushort_t mb = f2bf(r1);
    float r2 = r1 - bf2f(mb);
    ushort_t lb = f2bf(r2);
    sh[r][c] = hb; sm[r][c] = mb; sl[r][c] = lb;
  }
  __syncthreads();
  #pragma unroll
  for (int it = 0; it < 16; ++it){
    int idx = it*256 + t; int r = idx >> 6, c = idx & 63;
    size_t o = (size_t)(n0 + r)*4096 + k0 + c;
    H[o] = sh[c][r]; Mg[o] = sm[c][r]; L[o] = sl[c][r];
  }
}

// ---------------- MFMA GEMM (split-K=2) ------------------------------------
__global__ __launch_bounds__(256)
void k_mfma(const signed char* __restrict__ A8,
            const ushort_t* __restrict__ BH, const ushort_t* __restrict__ BM2,
            const ushort_t* __restrict__ BL,
            float* __restrict__ C0, float* __restrict__ C1, int N)
{
  __shared__ ushort_t Ab[64][72];
  __shared__ ushort_t Bb[3][64][72];
  const int t = threadIdx.x;
  const int m0 = blockIdx.y * 64, n0 = blockIdx.x * 64;
  const int kz = blockIdx.z;
  const int kbase = kz * 2048;
  float* C = kz ? C1 : C0;
  const int sr = t >> 2, sc = (t & 3) * 16;
  const int w = t >> 6, lane = t & 63;
  const int fr = lane & 15, fg = lane >> 4;

  int4 a_r = *reinterpret_cast<const int4*>(A8 + (size_t)(m0+sr)*4096 + kbase + sc);
  const ushort_t* bsrc0 = BH  + (size_t)(n0+sr)*4096 + kbase + sc;
  const ushort_t* bsrc1 = BM2 + (size_t)(n0+sr)*4096 + kbase + sc;
  const ushort_t* bsrc2 = BL  + (size_t)(n0+sr)*4096 + kbase + sc;
  int4 b0a = reinterpret_cast<const int4*>(bsrc0)[0], b0b = reinterpret_cast<const int4*>(bsrc0)[1];
  int4 b1a = reinterpret_cast<const int4*>(bsrc1)[0], b1b = reinterpret_cast<const int4*>(bsrc1)[1];
  int4 b2a = reinterpret_cast<const int4*>(bsrc2)[0], b2b = reinterpret_cast<const int4*>(bsrc2)[1];

  f32x4 acc[4][3];
  #pragma unroll
  for (int c = 0; c < 4; ++c)
    #pragma unroll
    for (int p = 0; p < 3; ++p)
      acc[c][p] = (f32x4){0.f, 0.f, 0.f, 0.f};

  for (int k0 = 0; k0 < 2048; k0 += 64){
    {
      alignas(16) ushort_t tmp[16];
      const signed char* ab = reinterpret_cast<const signed char*>(&a_r);
      #pragma unroll
      for (int i = 0; i < 16; ++i) tmp[i] = f2bf((float)(int)ab[i]);  // exact
      *reinterpret_cast<int4*>(&Ab[sr][sc])     = reinterpret_cast<int4*>(tmp)[0];
      *reinterpret_cast<int4*>(&Ab[sr][sc + 8]) = reinterpret_cast<int4*>(tmp)[1];
      *reinterpret_cast<int4*>(&Bb[0][sr][sc])     = b0a;
      *reinterpret_cast<int4*>(&Bb[0][sr][sc + 8]) = b0b;
      *reinterpret_cast<int4*>(&Bb[1][sr][sc])     = b1a;
      *reinterpret_cast<int4*>(&Bb[1][sr][sc + 8]) = b1b;
      *reinterpret_cast<int4*>(&Bb[2][sr][sc])     = b2a;
      *reinterpret_cast<int4*>(&Bb[2][sr][sc + 8]) = b2b;
    }
    __syncthreads();
    if (k0 + 64 < 2048){
      a_r = *reinterpret_cast<const int4*>(A8 + (size_t)(m0+sr)*4096 + kbase + (k0+64) + sc);
      const ushort_t* p0 = BH  + (size_t)(n0+sr)*4096 + kbase + (k0+64) + sc;
      const ushort_t* p1 = BM2 + (size_t)(n0+sr)*4096 + kbase + (k0+64) + sc;
      const ushort_t* p2 = BL  + (size_t)(n0+sr)*4096 + kbase + (k0+64) + sc;
      b0a = reinterpret_cast<const int4*>(p0)[0]; b0b = reinterpret_cast<const int4*>(p0)[1];
      b1a = reinterpret_cast<const int4*>(p1)[0]; b1b = reinterpret_cast<const int4*>(p1)[1];
      b2a = reinterpret_cast<const int4*>(p2)[0]; b2b = reinterpret_cast<const int4*>(p2)[1];
    }
    #pragma unroll
    for (int kk = 0; kk < 64; kk += 32){
      bf16x8 af = *reinterpret_cast<const bf16x8*>(&Ab[w*16 + fr][kk + fg*8]);
      #pragma unroll
      for (int c = 0; c < 4; ++c){
        const int bn = c*16 + fr;
        bf16x8 bh = *reinterpret_cast<const bf16x8*>(&Bb[0][bn][kk + fg*8]);
        acc[c][0] = __builtin_amdgcn_mfma_f32_16x16x32_bf16(af, bh, acc[c][0], 0, 0, 0);
        bf16x8 bm = *reinterpret_cast<const bf16x8*>(&Bb[1][bn][kk + fg*8]);
        acc[c][1] = __builtin_amdgcn_mfma_f32_16x16x32_bf16(af, bm, acc[c][1], 0, 0, 0);
        bf16x8 bl = *reinterpret_cast<const bf16x8*>(&Bb[2][bn][kk + fg*8]);
        acc[c][2] = __builtin_amdgcn_mfma_f32_16x16x32_bf16(af, bl, acc[c][2], 0, 0, 0);
      }
    }
    __syncthreads();
  }
  #pragma unroll
  for (int c = 0; c < 4; ++c){
    f32x4 s = acc[c][0] + acc[c][1];
    s = s + acc[c][2];
    #pragma unroll
    for (int r = 0; r < 4; ++r)
      C[(size_t)(m0 + w*16 + fg*4 + r)*N + n0 + c*16 + fr] = s[r];
  }
}

// ---------------- 2-way split-K reduce, float4 -----------------------------
__global__ __launch_bounds__(256)
void k_add2(const float* __restrict__ A, const float* __restrict__ B,
            float* __restrict__ O, int n4)
{
  int i = blockIdx.x*256 + threadIdx.x;
  if (i < n4){
    float4 a = reinterpret_cast<const float4*>(A)[i];
    float4 b = reinterpret_cast<const float4*>(B)[i];
    reinterpret_cast<float4*>(O)[i] = make_float4(a.x+b.x, a.y+b.y, a.z+b.z, a.w+b.w);
  }
}

// ---------------- Z = noise * exp(relu(LP)) + relu(MP) ---------------------
__global__ __launch_bounds__(256)
void k_z2(const float* __restrict__ MPLP, const float* __restrict__ noise,
          float* __restrict__ Z)
{
  int i = blockIdx.x*256 + threadIdx.x;
  int m = i >> 7, c = i & 127;
  float mp = fmaxf(MPLP[(size_t)m*256 + c], 0.0f);
  float lp = fmaxf(MPLP[(size_t)m*256 + 128 + c], 0.0f);
  Z[i] = noise[i]*expf(lp) + mp;
}

// ---------------- symmetric logits GEMM (f32) ------------------------------
__global__ __launch_bounds__(256)
void k_zzt(const float* __restrict__ Z, float* __restrict__ C)
{
  const int bx = blockIdx.x, by = blockIdx.y;
  if (by > bx) return;
  __shared__ float As[16][68];
  __shared__ float Bs[16][68];
  const int t = threadIdx.x, tx = t & 15, ty = t >> 4;
  const int m0 = by*64, n0 = bx*64;
  const int mA = t >> 2, kA = (t & 3) * 4;
  float acc[4][4] = {};
  for (int k0 = 0; k0 < 128; k0 += 16){
    float4 va = *reinterpret_cast<const float4*>(Z + (size_t)(m0+mA)*128 + k0 + kA);
    As[kA+0][mA]=va.x; As[kA+1][mA]=va.y; As[kA+2][mA]=va.z; As[kA+3][mA]=va.w;
    float4 vb = *reinterpret_cast<const float4*>(Z + (size_t)(n0+mA)*128 + k0 + kA);
    Bs[kA+0][mA]=vb.x; Bs[kA+1][mA]=vb.y; Bs[kA+2][mA]=vb.z; Bs[kA+3][mA]=vb.w;
    __syncthreads();
    #pragma unroll
    for (int kk = 0; kk < 16; ++kk) {
      float4 av = *reinterpret_cast<const float4*>(&As[kk][ty*4]);
      float4 bv = *reinterpret_cast<const float4*>(&Bs[kk][tx*4]);
      float a[4]={av.x,av.y,av.z,av.w};
      float b[4]={bv.x,bv.y,bv.z,bv.w};
      #pragma unroll
      for (int i=0;i<4;++i)
        #pragma unroll
        for (int j=0;j<4;++j)
          acc[i][j] = fmaf(a[i], b[j], acc[i][j]);
    }
    __syncthreads();
  }
  #pragma unroll
  for (int i=0;i<4;++i){
    float* cp = C + (size_t)(m0+ty*4+i)*NN + (n0 + tx*4);
    *reinterpret_cast<float4*>(cp) = make_float4(acc[i][0],acc[i][1],acc[i][2],acc[i][3]);
  }
  if (bx != by){
    for (int c0 = 0; c0 < 64; c0 += 16){
      __syncthreads();
      if (tx >= c0/4 && tx < c0/4 + 4){
        #pragma unroll
        for (int i=0;i<4;++i)
          #pragma unroll
          for (int j=0;j<4;++j)
            As[tx*4 + j - c0][ty*4 + i] = acc[i][j];
      }
      __syncthreads();
      const int c = t & 63, r0 = t >> 6;
      #pragma unroll
      for (int rr = 0; rr < 4; ++rr)
        C[(size_t)(n0 + c0 + r0 + rr*4)*NN + m0 + c] = As[r0 + rr*4][c];
    }
  }
}

// ---------------- M32xN64 tiled GEMM ---------------------------------------
template<typename TA>
__global__ __launch_bounds__(256)
void k_gemm32(const TA* __restrict__ A, const float* __restrict__ B,
              float* __restrict__ C, int M, int N, int K, int ldc,
              const float* __restrict__ rowscale, const float* __restrict__ bias,
              int flags)
{
  __shared__ float As[16][36];
  __shared__ float Bs[16][68];
  const int t  = threadIdx.x;
  const int tx = t & 15, ty = t >> 4;
  const int m0 = blockIdx.y * 32, n0 = blockIdx.x * 64;
  float acc[2][4] = {};
  for (int k0 = 0; k0 < K; k0 += 16) {
    if (t < 128){
      const int mA = t >> 2, kA = (t & 3) * 4;
      if constexpr (std::is_same<TA, float>::value) {
        float4 v = *reinterpret_cast<const float4*>(A + (size_t)(m0+mA)*K + (k0+kA));
        As[kA+0][mA]=v.x; As[kA+1][mA]=v.y; As[kA+2][mA]=v.z; As[kA+3][mA]=v.w;
      } else {
        int u = *reinterpret_cast<const int*>(A + (size_t)(m0+mA)*K + (k0+kA));
        As[kA+0][mA]=(float)(int)(signed char)( u       & 0xff);
        As[kA+1][mA]=(float)(int)(signed char)((u>>8)   & 0xff);
        As[kA+2][mA]=(float)(int)(signed char)((u>>16)  & 0xff);
        As[kA+3][mA]=(float)(int)(signed char)((u>>24)  & 0xff);
      }
    }
    {
      const int kB = t >> 4, nB = (t & 15) * 4;
      float4 w = *reinterpret_cast<const float4*>(B + (size_t)(k0+kB)*N + (n0+nB));
      Bs[kB][nB+0]=w.x; Bs[kB][nB+1]=w.y; Bs[kB][nB+2]=w.z; Bs[kB][nB+3]=w.w;
    }
    __syncthreads();
    #pragma unroll
    for (int kk = 0; kk < 16; ++kk) {
      float a0 = As[kk][ty*2+0];
      float a1 = As[kk][ty*2+1];
      float4 bv = *reinterpret_cast<const float4*>(&Bs[kk][tx*4]);
      float b[4]={bv.x,bv.y,bv.z,bv.w};
      #pragma unroll
      for (int j=0;j<4;++j){
        acc[0][j] = fmaf(a0, b[j], acc[0][j]);
        acc[1][j] = fmaf(a1, b[j], acc[1][j]);
      }
    }
    __syncthreads();
  }
  #pragma unroll
  for (int i=0;i<2;++i){
    const int m = m0 + ty*2 + i;
    const float rsv = (flags & F_RS) ? rowscale[m] : 1.0f;
    float* cp = C + (size_t)m*ldc + (n0 + tx*4);
    float o[4];
    #pragma unroll
    for (int j=0;j<4;++j){
      float v = acc[i][j] * rsv;
      if (flags & F_BIAS) v += bias[n0 + tx*4 + j];
      if (flags & F_ACC)  v += cp[j];
      if (flags & F_RELU) v = fmaxf(v, 0.0f);
      o[j] = v;
    }
    *reinterpret_cast<float4*>(cp) = make_float4(o[0],o[1],o[2],o[3]);
  }
}

// ---------------- M32 tiled GEMM, B transposed -----------------------------
__global__ __launch_bounds__(256)
void k_gemm32T(const float* __restrict__ A, const float* __restrict__ B,
               float* __restrict__ C, int M, int N, int K, int ldc)
{
  __shared__ float As[16][36];
  __shared__ float Bs[16][68];
  const int t  = threadIdx.x;
  const int tx = t & 15, ty = t >> 4;
  const int m0 = blockIdx.y * 32, n0 = blockIdx.x * 64;
  float acc[2][4] = {};
  for (int k0 = 0; k0 < K; k0 += 16) {
    if (t < 128){
      const int mA = t >> 2, kA = (t & 3) * 4;
      float4 v = *reinterpret_cast<const float4*>(A + (size_t)(m0+mA)*K + (k0+kA));
      As[kA+0][mA]=v.x; As[kA+1][mA]=v.y; As[kA+2][mA]=v.z; As[kA+3][mA]=v.w;
    }
    {
      const int nB = t >> 2, kB = (t & 3) * 4;
      float4 w = *reinterpret_cast<const float4*>(B + (size_t)(n0+nB)*K + (k0+kB));
      Bs[kB+0][nB]=w.x; Bs[kB+1][nB]=w.y; Bs[kB+2][nB]=w.z; Bs[kB+3][nB]=w.w;
    }
    __syncthreads();
    #pragma unroll
    for (int kk = 0; kk < 16; ++kk) {
      float a0 = As[kk][ty*2+0];
      float a1 = As[kk][ty*2+1];
      float4 bv = *reinterpret_cast<const float4*>(&Bs[kk][tx*4]);
      float b[4]={bv.x,bv.y,bv.z,bv.w};
      #pragma unroll
      for (int j=0;j<4;++j){
        acc[0][j] = fmaf(a0, b[j], acc[0][j]);
        acc[1][j] = fmaf(a1, b[j], acc[1][j]);
      }
    }
    __syncthreads();
  }
  #pragma unroll
  for (int i=0;i<2;++i){
    const int m = m0 + ty*2 + i;
    float* cp = C + (size_t)m*ldc + (n0 + tx*4);
    *reinterpret_cast<float4*>(cp) = make_float4(acc[i][0],acc[i][1],acc[i][2],acc[i][3]);
  }
}

// ---------------- fused dual GEMM ------------------------------------------
__global__ __launch_bounds__(256)
void k_fc(const float* __restrict__ A1, const float* __restrict__ B1,
          const float* __restrict__ bias,
          const float* __restrict__ A2, const float* __restrict__ B2,
          const float* __restrict__ rowscale,
          float* __restrict__ C, int N, int K1, int K2, int relu)
{
  __shared__ float As[16][36];
  __shared__ float Bs[16][68];
  const int t  = threadIdx.x;
  const int tx = t & 15, ty = t >> 4;
  const int m0 = blockIdx.y * 32, n0 = blockIdx.x * 64;
  float acc1[2][4] = {};
  float acc2[2][4] = {};
  for (int k0 = 0; k0 < K1; k0 += 16) {
    if (t < 128){
      const int mA = t >> 2, kA = (t & 3) * 4;
      float4 v = *reinterpret_cast<const float4*>(A1 + (size_t)(m0+mA)*K1 + (k0+kA));
      As[kA+0][mA]=v.x; As[kA+1][mA]=v.y; As[kA+2][mA]=v.z; As[kA+3][mA]=v.w;
    }
    {
      const int kB = t >> 4, nB = (t & 15) * 4;
      float4 w = *reinterpret_cast<const float4*>(B1 + (size_t)(k0+kB)*N + (n0+nB));
      Bs[kB][nB+0]=w.x; Bs[kB][nB+1]=w.y; Bs[kB][nB+2]=w.z; Bs[kB][nB+3]=w.w;
    }
    __syncthreads();
    #pragma unroll
    for (int kk = 0; kk < 16; ++kk) {
      float a0 = As[kk][ty*2+0];
      float a1 = As[kk][ty*2+1];
      float4 bv = *reinterpret_cast<const float4*>(&Bs[kk][tx*4]);
      float b[4]={bv.x,bv.y,bv.z,bv.w};
      #pragma unroll
      for (int j=0;j<4;++j){
        acc1[0][j] = fmaf(a0, b[j], acc1[0][j]);
        acc1[1][j] = fmaf(a1, b[j], acc1[1][j]);
      }
    }
    __syncthreads();
  }
  for (int k0 = 0; k0 < K2; k0 += 16) {
    if (t < 128){
      const int mA = t >> 2, kA = (t & 3) * 4;
      float4 v = *reinterpret_cast<const float4*>(A2 + (size_t)(m0+mA)*K2 + (k0+kA));
      As[kA+0][mA]=v.x; As[kA+1][mA]=v.y; As[kA+2][mA]=v.z; As[kA+3][mA]=v.w;
    }
    {
      const int kB = t >> 4, nB = (t & 15) * 4;
      float4 w = *reinterpret_cast<const float4*>(B2 + (size_t)(k0+kB)*N + (n0+nB));
      Bs[kB][nB+0]=w.x; Bs[kB][nB+1]=w.y; Bs[kB][nB+2]=w.z; Bs[kB][nB+3]=w.w;
    }
    __syncthreads();
    #pragma unroll
    for (int kk = 0; kk < 16; ++kk) {
      float a0 = As[kk][ty*2+0];
      float a1 = As[kk][ty*2+1];
      float4 bv = *reinterpret_cast<const float4*>(&Bs[kk][tx*4]);
      float b[4]={bv.x,bv.y,bv.z,bv.w};
      #pragma unroll
      for (int j=0;j<4;++j){
        acc2[0][j] = fmaf(a0, b[j], acc2[0][j]);
        acc2[1][j] = fmaf(a1, b[j], acc2[1][j]);
      }
    }
    __syncthreads();
  }
  #pragma unroll
  for (int i=0;i<2;++i){
    const int m = m0 + ty*2 + i;
    const float rsv = rowscale[m];
    float* cp = C + (size_t)m*N + (n0 + tx*4);
    float o[4];
    #pragma unroll
    for (int j=0;j<4;++j){
      float t1 = acc1[i][j] + bias[n0 + tx*4 + j];
      float v  = acc2[i][j] * rsv;
      v += t1;
      if (relu) v = fmaxf(v, 0.0f);
      o[j] = v;
    }
    *reinterpret_cast<float4*>(cp) = make_float4(o[0],o[1],o[2],o[3]);
  }
}

// ---------------- weight concat --------------------------------------------
__global__ __launch_bounds__(256)
void k_wcat(const float* __restrict__ Wm, const float* __restrict__ Wl,
            float* __restrict__ Wcat)
{
  int idx = blockIdx.x*256 + threadIdx.x;
  int row = idx >> 8, col = idx & 255;
  Wcat[idx] = (col < 128) ? Wm[row*128 + col] : Wl[row*128 + (col - 128)];
}

// ---------------- per-row compact-gather SpMM ------------------------------
template<int D>
__global__ __launch_bounds__(256)
void k_spmmF(const float* __restrict__ A, const float* __restrict__ B,
             float* __restrict__ C)
{
  const int row = blockIdx.x, t = threadIdx.x;
  const int lane = t & 63, wv = t >> 6;
  __shared__ int   sc[288];
  __shared__ float sv[288];
  __shared__ int wtot[4];
  __shared__ int nsh;
  const float4* r4 = reinterpret_cast<const float4*>(A + (size_t)row*NN) + t*4;
  float lv[16];
  #pragma unroll
  for (int q=0;q<4;++q){
    float4 v = r4[q];
    lv[q*4+0]=v.x; lv[q*4+1]=v.y; lv[q*4+2]=v.z; lv[q*4+3]=v.w;
  }
  int c = 0;
  #pragma unroll
  for (int k=0;k<16;++k) c += (lv[k] != 0.0f);
  int inc = c;
  #pragma unroll
  for (int off=1; off<64; off<<=1){
    int v = __shfl_up(inc, off, 64);
    if (lane >= off) inc += v;
  }
  if (lane == 63) wtot[wv] = inc;
  __syncthreads();
  int wbase = 0;
  #pragma unroll
  for (int ww=0; ww<3; ++ww) if (ww < wv) wbase += wtot[ww];
  int pos = wbase + inc - c;
  #pragma unroll
  for (int k=0;k<16;++k){
    if (lv[k] != 0.0f){
      if (pos >= 0 && pos < 288){ sc[pos] = t*16+k; sv[pos] = lv[k]; }
      pos++;
    }
  }
  if (t == 255){
    int tot = wbase + inc;
    nsh = (tot < 288) ? tot : 288;
  }
  __syncthreads();
  const int n = nsh;
  float acc = 0.f;
  int s = 0;
  for (; s+4 <= n; s += 4){
    float x0 = B[(size_t)sc[s+0]*D + t];
    float x1 = B[(size_t)sc[s+1]*D + t];
    float x2 = B[(size_t)sc[s+2]*D + t];
    float x3 = B[(size_t)sc[s+3]*D + t];
    acc = fmaf(sv[s+0], x0, acc);
    acc = fmaf(sv[s+1], x1, acc);
    acc = fmaf(sv[s+2], x2, acc);
    acc = fmaf(sv[s+3], x3, acc);
  }
  for (; s < n; ++s) acc = fmaf(sv[s], B[(size_t)sc[s]*D + t], acc);
  C[(size_t)row*D + t] = acc;
}

// ---------------- selection -------------------------------------------------
__global__ __launch_bounds__(256)
void k_initstats(SelParams* p)
{
  int t = threadIdx.x;
  if (t == 0){
    p->min_ord = 0xFFFFFFFFu; p->max_ord = 0u; p->n_up = 0u;
    p->rm_prefix = 0u; p->add_prefix = 0u;
  }
  p->hist_rm[t] = 0u; p->hist_add[t] = 0u;
}

__global__ __launch_bounds__(256)
void k_stats1(const float* __restrict__ L, const float* __restrict__ adj,
              unsigned long long* __restrict__ mask, SelParams* __restrict__ p)
{
  unsigned mn=0xFFFFFFFFu, mx=0u, cnt=0u;
  size_t g = (size_t)blockIdx.x*256 + threadIdx.x;
  const size_t stride = (size_t)gridDim.x*256;
  for (; g < 262144; g += stride){
    const int i  = (int)(g >> 6);
    const int jb = (int)(g & 63) << 6;
    unsigned long long m = 0ull;
    if (jb + 63 > i){
      const float4* a4 = reinterpret_cast<const float4*>(adj + (size_t)i*NN + jb);
      const float4* l4 = reinterpret_cast<const float4*>(L   + (size_t)i*NN + jb);
      for (int w = 0; w < 16; ++w){
        const int j0 = jb + w*4;
        if (j0 + 3 <= i) continue;
        float4 av = a4[w]; float4 lv = l4[w];
        float ae[4]={av.x,av.y,av.z,av.w};
        float le[4]={lv.x,lv.y,lv.z,lv.w};
        #pragma unroll
        for (int e=0;e<4;++e){
          const int jj = j0 + e;
          if (jj > i){
            if (ae[e] != 0.0f){ m |= 1ull << (jj & 63); cnt++; }
            unsigned o = ordenc(le[e]);
            mn = (o < mn) ? o : mn;
            mx = (o > mx) ? o : mx;
          }
        }
      }
    }
    mask[g] = m;
  }
  __shared__ unsigned smn[256], smx[256], sc[256];
  int t = threadIdx.x;
  smn[t]=mn; smx[t]=mx; sc[t]=cnt; __syncthreads();
  for (int s=128; s>0; s>>=1){
    if (t < s){
      smn[t] = (smn[t+s] < smn[t]) ? smn[t+s] : smn[t];
      smx[t] = (smx[t+s] > smx[t]) ? smx[t+s] : smx[t];
      sc[t] += sc[t+s];
    }
    __syncthreads();
  }
  if (t == 0){
    atomicMin(&p->min_ord, smn[0]);
    atomicMax(&p->max_ord, smx[0]);
    atomicAdd(&p->n_up, sc[0]);
  }
}

__global__ void k_stats2(SelParams* p)
{
  float mnv = orddec_ok(p->min_ord), mxv = orddec_ok(p->max_ord);
  float lo = fminf(mnv, 0.0f), hi = fmaxf(mxv, 0.0f);
  p->lo = lo;
  p->M  = hi - lo;
  p->c0 = (0.0f - lo) / p->M;
  p->n_change = p->n_up;
}

__global__ __launch_bounds__(256)
void k_hist2(const float* __restrict__ L, const unsigned long long* __restrict__ mask,
             SelParams* __restrict__ p, int shift)
{
  __shared__ unsigned hr[256], ha[256];
  const int t = threadIdx.x;
  hr[t]=0u; ha[t]=0u; __syncthreads();
  const float lo = p->lo, Mv = p->M;
  const unsigned pr = p->rm_prefix, pa = p->add_prefix;
  const float4* L4 = reinterpret_cast<const float4*>(L);
  size_t q = (size_t)blockIdx.x*256 + t;
  const size_t stride = (size_t)gridDim.x*256;
  for (; q < TTOT/4; q += stride){
    const int i = (int)(q >> 10);
    const int j = (int)(q & 1023) << 2;
    if (j + 3 <= i) continue;
    float4 l = L4[q];
    const unsigned long long w = mask[q >> 4];
    float le[4]={l.x,l.y,l.z,l.w};
    #pragma unroll
    for (int e=0;e<4;++e){
      const int jj = j + e;
      if (jj <= i) continue;
      const unsigned key = __float_as_uint((le[e] - lo) / Mv);
      if (key == 0u) continue;
      const bool edge = (w >> (jj & 63)) & 1ull;
      if (edge){
        if (shift == 24 || (key >> (shift+8)) == pr) atomicAdd(&hr[(key>>shift)&255u], 1u);
      } else {
        if (shift == 24 || (key >> (shift+8)) == pa) atomicAdd(&ha[(key>>shift)&255u], 1u);
      }
    }
  }
  __syncthreads();
  if (hr[t]) atomicAdd(&p->hist_rm[t], hr[t]);
  if (ha[t]) atomicAdd(&p->hist_add[t], ha[t]);
}

__global__ __launch_bounds__(256)
void k_scan2(SelParams* __restrict__ p, int shift)
{
  const int t = threadIdx.x;
  if (t == 0){
    const unsigned c0k  = __float_as_uint(p->c0);
    const unsigned n_up = p->n_up;
    {
      unsigned injb = 300u, inj = 0u;
      if (c0k != 0u && (shift == 24 || (c0k >> (shift+8)) == p->rm_prefix)){
        injb = (c0k >> shift) & 255u; inj = n_up;
      }
      unsigned k;
      if (shift == 24){
        unsigned tot = inj;
        for (int d=0; d<256; ++d) tot += p->hist_rm[d];
        k = (tot < p->n_change) ? tot : p->n_change;
      } else k = p->rm_k;
      unsigned cum = 0u, digit = 255u;
      for (int d=0; d<256; ++d){
        unsigned hd = p->hist_rm[d] + (((unsigned)d == injb) ? inj : 0u);
        if (cum + hd >= k){ digit = (unsigned)d; k -= cum; break; }
        cum += hd;
      }
      p->rm_prefix = (p->rm_prefix << 8) | digit;
      p->rm_k = k;
      if (shift == 0) p->t_rm = __uint_as_float(p->rm_prefix);
    }
    {
      unsigned injb = 300u, inj = 0u;
      if (c0k != 0u && (shift == 24 || (c0k >> (shift+8)) == p->add_prefix)){
        injb = (c0k >> shift) & 255u;
        inj  = 8386560u - n_up + 4096u;
      }
      unsigned k;
      if (shift == 24){
        unsigned tot = inj;
        for (int d=0; d<256; ++d) tot += p->hist_add[d];
        k = (tot < p->n_change) ? tot : p->n_change;
      } else k = p->add_k;
      unsigned cum = 0u, digit = 0u;
      for (int d=255; d>=0; --d){
        unsigned hd = p->hist_add[d] + (((unsigned)d == injb) ? inj : 0u);
        if (cum + hd >= k){ digit = (unsigned)d; k -= cum; break; }
        cum += hd;
      }
      p->add_prefix = (p->add_prefix << 8) | digit;
      p->add_k = k;
      if (shift == 0) p->t_add = __uint_as_float(p->add_prefix);
    }
  }
  __syncthreads();
  p->hist_rm[t] = 0u; p->hist_add[t] = 0u;
}

// ---------------- build adj_new ---------------------------------------------
__device__ __forceinline__ int adjval(bool edge, float v, float c0v, float trm, float tad)
{
  int rmU = (edge && v   >  0.0f && v   <= trm) ? 1 : 0;
  int rmL = (edge && c0v >  0.0f && c0v <= trm) ? 1 : 0;
  int adU = (!edge && v   >= tad) ? 1 : 0;
  int adL = (!edge && c0v >= tad) ? 1 : 0;
  return (edge ? 1 : 0) - rmU - rmL + adU + adL;
}

__global__ __launch_bounds__(256)
void k_apply(const float* __restrict__ L, const unsigned long long* __restrict__ mask,
             const SelParams* __restrict__ p, signed char* __restrict__ A8)
{
  const int bx = blockIdx.x, by = blockIdx.y;
  if (by > bx) return;
  const float lo=p->lo, Mv=p->M, c0v=p->c0, trm=p->t_rm, tad=p->t_add;
  const int i0 = by*64, j0 = bx*64, t = threadIdx.x;
  __shared__ signed char Vs[64][65];
  if (bx == by){
    for (int it=0; it<16; ++it){
      int e = it*256 + t; int r = e>>6, c = e&63;
      size_t idx = (size_t)(i0+r)*NN + (j0+c);
      if (r < c){
        bool edge = (mask[idx>>6] >> ((j0+c) & 63)) & 1ull;
        float v = (L[idx] - lo) / Mv;
        int val = adjval(edge, v, c0v, trm, tad);
        A8[idx] = (signed char)val;
        Vs[c][r] = (signed char)val;
      } else if (r == c){
        A8[idx] = 1;
      }
    }
    __syncthreads();
    for (int it=0; it<16; ++it){
      int e = it*256 + t; int r = e>>6, c = e&63;
      if (r > c) A8[(size_t)(i0+r)*NN + (j0+c)] = Vs[r][c];
    }
  } else {
    for (int it=0; it<16; ++it){
      int e = it*256 + t; int r = e>>6, c = e&63;
      size_t idx = (size_t)(i0+r)*NN + (j0+c);
      bool edge = (mask[idx>>6] >> ((j0+c) & 63)) & 1ull;
      float v = (L[idx] - lo) / Mv;
      int val = adjval(edge, v, c0v, trm, tad);
      A8[idx] = (signed char)val;
      Vs[c][r] = (signed char)val;
    }
    __syncthreads();
    for (int it=0; it<16; ++it){
      int e = it*256 + t; int r = e>>6, c = e&63;
      A8[(size_t)(j0+r)*NN + (i0+c)] = Vs[r][c];
    }
  }
}

// ---------------- per-row scale for mean_neigh ------------------------------
__global__ __launch_bounds__(256)
void k_rowsum8(const signed char* __restrict__ A8, float* __restrict__ s_mean)
{
  const int row = blockIdx.x, t = threadIdx.x;
  const int4 w = reinterpret_cast<const int4*>(A8 + (size_t)row*NN)[t];
  int s = 0, a = 0;
  int vs[4] = {w.x, w.y, w.z, w.w};
  #pragma unroll
  for (int q=0; q<4; ++q){
    int u = vs[q];
    #pragma unroll
    for (int b=0; b<4; ++b){
      int c = (int)(signed char)((u >> (8*b)) & 0xff);
      s += c; a += (c < 0) ? -c : c;
    }
  }
  __shared__ int rs_[256], ra_[256];
  rs_[t]=s; ra_[t]=a; __syncthreads();
  for (int st=128; st>0; st>>=1){
    if (t < st){ rs_[t]+=rs_[t+st]; ra_[t]+=ra_[t+st]; }
    __syncthreads();
  }
  if (t == 0){
    float rs = (float)rs_[0], ra = (float)ra_[0];
    float A = fmaxf(ra, 1e-12f);
    s_mean[row] = (1.0f / A) / (rs / A + 1e-7f);
  }
}

// ---------------- row log_softmax (512 cols, in place) ----------------------
__global__ __launch_bounds__(256)
void k_lsm(float* __restrict__ X)
{
  const int row = blockIdx.x, t = threadIdx.x;
  float* x = X + (size_t)row*512;
  float v0 = x[t], v1 = x[t+256];
  __shared__ float red[256];
  red[t] = fmaxf(v0, v1); __syncthreads();
  for (int s=128; s>0; s>>=1){
    if (t < s) red[t] = fmaxf(red[t], red[t+s]);
    __syncthreads();
  }
  float m = red[0]; __syncthreads();
  red[t] = expf(v0-m) + expf(v1-m); __syncthreads();
  for (int s=128; s>0; s>>=1){
    if (t < s) red[t] += red[t+s];
    __syncthreads();
  }
  float ls = logf(red[0]);
  x[t]     = (v0 - m) - ls;
  x[t+256] = (v1 - m) - ls;
}

// ---------------- driver ---------------------------------------------------
extern "C" void kernel_launch(void* const* d_in, const int* in_sizes, int n_in,
                              void* d_out, int out_size, void* d_ws, size_t ws_size,
                              hipStream_t stream)
{
  (void)in_sizes; (void)n_in; (void)out_size; (void)ws_size;
  const float* adj_norm = (const float*)d_in[0];
  const float* adj_ori  = (const float*)d_in[1];
  const float* feats    = (const float*)d_in[2];
  const float* img      = (const float*)d_in[3];
  const float* csd_img  = (const float*)d_in[5];
  const float* noise    = (const float*)d_in[6];
  const float* Wb       = (const float*)d_in[7];
  const float* Wm       = (const float*)d_in[8];
  const float* Wl       = (const float*)d_in[9];
  const float* fc1W     = (const float*)d_in[10];
  const float* fc1b     = (const float*)d_in[11];
  const float* fc2W     = (const float*)d_in[12];
  const float* fc2b     = (const float*)d_in[13];

  float* out    = (float*)d_out;
  float* out_pt = out;                 // preds_total 4096x64
  float* out_ft = out + 262144;        // feat_total  4096x512 (free until fc2)
  float* out_pi = out + 2359296;       // preds_img   4096x64
  float* out_lg = out + 2621440;       // adj_logits  4096x4096

  char* W = (char*)d_ws;
  signed char* adj8 = (signed char*)W;                              // 16MB
  float* bufA   = (float*)(W + (16u<<20));                          // 8MB
  float* bufB   = (float*)(W + (24u<<20));                          // 4MB
  float* HMHL   = (float*)(W + (28u<<20));                          // 4MB
  float* MPLP   = (float*)(W + (32u<<20));                          // 4MB
  float* Z      = (float*)(W + (36u<<20));                          // 2MB
  unsigned long long* mask = (unsigned long long*)(W + (38u<<20));  // 2MB
  float* p2q0   = (float*)(W + (40u<<20));                          // 4MB
  float* s_mean = (float*)(W + (44u<<20));                          // 16KB
  SelParams* sp = (SelParams*)(W + (44u<<20) + 65536);
  float* Wcat   = (float*)(W + (45u<<20));                          // 256KB
  // B bf16 plane regions (dead buffers after apply):
  ushort_t* BT1h = (ushort_t*)(W + (28u<<20));   // 4MB
  ushort_t* BT1m = (ushort_t*)(W + (32u<<20));   // 4MB
  ushort_t* BT1l = (ushort_t*)(W + (36u<<20));   // 4MB (Z+mask region, dead after apply)
  ushort_t* BT2h = (ushort_t*)(W + (28u<<20));   // 2MB
  ushort_t* BT2m = (ushort_t*)(W + (30u<<20));   // 2MB
  ushort_t* BT2l = (ushort_t*)(W + (32u<<20));   // 2MB

  dim3 B(256);
  auto G32 = [](int M, int N){ return dim3((unsigned)(N/64), (unsigned)(M/32)); };

  // ---- ep_net ----
  k_gemm32<float><<<G32(4096,256),B,0,stream>>>(img, Wb, bufA, 4096,256,512,256, nullptr,nullptr,0);  // T1
  k_spmmF<256><<<4096,B,0,stream>>>(adj_norm, bufA, bufB);                                            // hidden
  k_wcat<<<256,B,0,stream>>>(Wm, Wl, Wcat);
  k_gemm32<float><<<G32(4096,256),B,0,stream>>>(bufB, Wcat, HMHL, 4096,256,256,256, nullptr,nullptr,0); // [HM|HL]
  k_spmmF<256><<<4096,B,0,stream>>>(adj_norm, HMHL, MPLP);                                            // [MP|LP]
  k_z2<<<2048,B,0,stream>>>(MPLP, noise, Z);
  k_zzt<<<dim3(64,64),B,0,stream>>>(Z, out_lg);                                                       // logits (f32)

  // ---- edge rewiring ----
  k_initstats<<<1,B,0,stream>>>(sp);
  k_stats1<<<1024,B,0,stream>>>(out_lg, adj_ori, mask, sp);
  k_stats2<<<1,1,0,stream>>>(sp);
  for (int shift = 24; shift >= 0; shift -= 8){
    k_hist2<<<2048,B,0,stream>>>(out_lg, mask, sp, shift);
    k_scan2<<<1,B,0,stream>>>(sp, shift);
  }
  k_apply<<<dim3(64,64),B,0,stream>>>(out_lg, mask, sp, adj8);

  // ---- row scales ----
  k_rowsum8<<<4096,B,0,stream>>>(adj8, s_mean);

  // ---- nc_net (MFMA split-K=2, r19 configuration) ----
  k_b3t<512><<<dim3(8,64),B,0,stream>>>(feats, BT1h, BT1m, BT1l);
  k_mfma<<<dim3(8,64,2),B,0,stream>>>(adj8, BT1h, BT1m, BT1l, bufA, out_ft, 512); // P halves
  k_add2<<<2048,B,0,stream>>>(bufA, out_ft, bufA, 524288);                        // P
  k_fc<<<G32(4096,256),B,0,stream>>>(feats, fc1W, fc1b, bufA, fc1W + 512*256, s_mean,
                                     bufB, 256, 512, 512, 1);                     // h1
  k_b3t<256><<<dim3(4,64),B,0,stream>>>(bufB, BT2h, BT2m, BT2l);
  k_mfma<<<dim3(4,64,2),B,0,stream>>>(adj8, BT2h, BT2m, BT2l, p2q0, out_ft, 256); // P2 halves
  k_add2<<<1024,B,0,stream>>>(p2q0, out_ft, bufA, 262144);                        // P2
  k_fc<<<G32(4096,512),B,0,stream>>>(bufB, fc2W, fc2b, bufA, fc2W + 256*512, s_mean,
                                     out_ft, 512, 256, 256, 0);
  k_lsm<<<4096,B,0,stream>>>(out_ft);

  // ---- heads ----
  k_gemm32T<<<G32(4096,64),B,0,stream>>>(out_ft, csd_img, out_pt, 4096,64,512,64);
  k_gemm32T<<<G32(4096,64),B,0,stream>>>(img, csd_img, out_pi, 4096,64,512,64);
}

// Round 24
// 824.925 us; speedup vs baseline: 1.1643x; 1.0242x over previous
//
#include <hip/hip_runtime.h>
#include <type_traits>
#include <stdint.h>

#define NN 4096
#define TTOT 16777216UL

enum { F_RELU=1, F_ACC=2, F_RS=4, F_BIAS=8 };

typedef unsigned short ushort_t;
using bf16x8 = __attribute__((ext_vector_type(8))) short;
using f32x4  = __attribute__((ext_vector_type(4))) float;

struct SelParams {
  unsigned min_ord, max_ord, n_up;
  float lo, M, c0;
  unsigned n_change, rm_prefix, rm_k, add_prefix, add_k;
  float t_rm, t_add;
  unsigned hist_rm[256], hist_add[256];
};

__device__ __forceinline__ unsigned ordenc(float x){
  unsigned u = __float_as_uint(x);
  return (u & 0x80000000u) ? ~u : (u | 0x80000000u);
}
__device__ __forceinline__ float orddec_ok(unsigned o){
  unsigned u = (o & 0x80000000u) ? (o ^ 0x80000000u) : ~o;
  return __uint_as_float(u);
}
__device__ __forceinline__ ushort_t f2bf(float x){
  unsigned u = __float_as_uint(x);
  return (ushort_t)((u + 0x7FFFu + ((u >> 16) & 1u)) >> 16);
}
__device__ __forceinline__ float bf2f(ushort_t h){
  return __uint_as_float(((unsigned)h) << 16);
}

// ---------------- B -> 3 exact bf16 planes, transposed ---------------------
template<int DN>
__global__ __launch_bounds__(256)
void k_b3t(const float* __restrict__ Bsrc, ushort_t* __restrict__ H,
           ushort_t* __restrict__ Mg, ushort_t* __restrict__ L)
{
  __shared__ ushort_t sh[64][65], sm[64][65], sl[64][65];
  const int t = threadIdx.x;
  const int n0 = blockIdx.x * 64, k0 = blockIdx.y * 64;
  #pragma unroll
  for (int it = 0; it < 16; ++it){
    int idx = it*256 + t; int r = idx >> 6, c = idx & 63;
    float x  = Bsrc[(size_t)(k0 + r)*DN + n0 + c];
    ushort_t hb = f2bf(x);
    float r1 = x - bf2f(hb);
    ushort_t mb = f2bf(r1);
    float r2 = r1 - bf2f(mb);
    ushort_t lb = f2bf(r2);
    sh[r][c] = hb; sm[r][c] = mb; sl[r][c] = lb;
  }
  __syncthreads();
  #pragma unroll
  for (int it = 0; it < 16; ++it){
    int idx = it*256 + t; int r = idx >> 6, c = idx & 63;
    size_t o = (size_t)(n0 + r)*4096 + k0 + c;
    H[o] = sh[c][r]; Mg[o] = sm[c][r]; L[o] = sl[c][r];
  }
}

// ---------------- MFMA GEMM (split-K=2), wave = 4 m-tiles x 1 n-tile -------
// Identical block shape/staging/LDS/epilogue-order to r19; only the wave->
// tile mapping transposed (wave w owns n-cols [w*16,w*16+16), all 64 m-rows).
// Per kk-half: 4 A-reads + 3 B-reads feed 12 MFMA (was 1+12). Each output
// element's per-plane K-ascending MFMA chain and (hi+mid)+lo epilogue are
// unchanged -> output BIT-IDENTICAL to r19/r23.
__global__ __launch_bounds__(256)
void k_mfma(const signed char* __restrict__ A8,
            const ushort_t* __restrict__ BH, const ushort_t* __restrict__ BM2,
            const ushort_t* __restrict__ BL,
            float* __restrict__ C0, float* __restrict__ C1, int N)
{
  __shared__ ushort_t Ab[64][72];
  __shared__ ushort_t Bb[3][64][72];
  const int t = threadIdx.x;
  const int m0 = blockIdx.y * 64, n0 = blockIdx.x * 64;
  const int kz = blockIdx.z;
  const int kbase = kz * 2048;
  float* C = kz ? C1 : C0;
  const int sr = t >> 2, sc = (t & 3) * 16;
  const int w = t >> 6, lane = t & 63;
  const int fr = lane & 15, fg = lane >> 4;

  int4 a_r = *reinterpret_cast<const int4*>(A8 + (size_t)(m0+sr)*4096 + kbase + sc);
  const ushort_t* bsrc0 = BH  + (size_t)(n0+sr)*4096 + kbase + sc;
  const ushort_t* bsrc1 = BM2 + (size_t)(n0+sr)*4096 + kbase + sc;
  const ushort_t* bsrc2 = BL  + (size_t)(n0+sr)*4096 + kbase + sc;
  int4 b0a = reinterpret_cast<const int4*>(bsrc0)[0], b0b = reinterpret_cast<const int4*>(bsrc0)[1];
  int4 b1a = reinterpret_cast<const int4*>(bsrc1)[0], b1b = reinterpret_cast<const int4*>(bsrc1)[1];
  int4 b2a = reinterpret_cast<const int4*>(bsrc2)[0], b2b = reinterpret_cast<const int4*>(bsrc2)[1];

  f32x4 acc[4][3];   // [m-tile][plane]
  #pragma unroll
  for (int mt = 0; mt < 4; ++mt)
    #pragma unroll
    for (int p = 0; p < 3; ++p)
      acc[mt][p] = (f32x4){0.f, 0.f, 0.f, 0.f};

  for (int k0 = 0; k0 < 2048; k0 += 64){
    {
      alignas(16) ushort_t tmp[16];
      const signed char* ab = reinterpret_cast<const signed char*>(&a_r);
      #pragma unroll
      for (int i = 0; i < 16; ++i) tmp[i] = f2bf((float)(int)ab[i]);  // exact
      *reinterpret_cast<int4*>(&Ab[sr][sc])     = reinterpret_cast<int4*>(tmp)[0];
      *reinterpret_cast<int4*>(&Ab[sr][sc + 8]) = reinterpret_cast<int4*>(tmp)[1];
      *reinterpret_cast<int4*>(&Bb[0][sr][sc])     = b0a;
      *reinterpret_cast<int4*>(&Bb[0][sr][sc + 8]) = b0b;
      *reinterpret_cast<int4*>(&Bb[1][sr][sc])     = b1a;
      *reinterpret_cast<int4*>(&Bb[1][sr][sc + 8]) = b1b;
      *reinterpret_cast<int4*>(&Bb[2][sr][sc])     = b2a;
      *reinterpret_cast<int4*>(&Bb[2][sr][sc + 8]) = b2b;
    }
    __syncthreads();
    if (k0 + 64 < 2048){
      a_r = *reinterpret_cast<const int4*>(A8 + (size_t)(m0+sr)*4096 + kbase + (k0+64) + sc);
      const ushort_t* p0 = BH  + (size_t)(n0+sr)*4096 + kbase + (k0+64) + sc;
      const ushort_t* p1 = BM2 + (size_t)(n0+sr)*4096 + kbase + (k0+64) + sc;
      const ushort_t* p2 = BL  + (size_t)(n0+sr)*4096 + kbase + (k0+64) + sc;
      b0a = reinterpret_cast<const int4*>(p0)[0]; b0b = reinterpret_cast<const int4*>(p0)[1];
      b1a = reinterpret_cast<const int4*>(p1)[0]; b1b = reinterpret_cast<const int4*>(p1)[1];
      b2a = reinterpret_cast<const int4*>(p2)[0]; b2b = reinterpret_cast<const int4*>(p2)[1];
    }
    #pragma unroll
    for (int kk = 0; kk < 64; kk += 32){
      const int bn = w*16 + fr;
      bf16x8 bh = *reinterpret_cast<const bf16x8*>(&Bb[0][bn][kk + fg*8]);
      bf16x8 bm = *reinterpret_cast<const bf16x8*>(&Bb[1][bn][kk + fg*8]);
      bf16x8 bl = *reinterpret_cast<const bf16x8*>(&Bb[2][bn][kk + fg*8]);
      #pragma unroll
      for (int mt = 0; mt < 4; ++mt){
        bf16x8 af = *reinterpret_cast<const bf16x8*>(&Ab[mt*16 + fr][kk + fg*8]);
        acc[mt][0] = __builtin_amdgcn_mfma_f32_16x16x32_bf16(af, bh, acc[mt][0], 0, 0, 0);
        acc[mt][1] = __builtin_amdgcn_mfma_f32_16x16x32_bf16(af, bm, acc[mt][1], 0, 0, 0);
        acc[mt][2] = __builtin_amdgcn_mfma_f32_16x16x32_bf16(af, bl, acc[mt][2], 0, 0, 0);
      }
    }
    __syncthreads();
  }
  #pragma unroll
  for (int mt = 0; mt < 4; ++mt){
    f32x4 s = acc[mt][0] + acc[mt][1];
    s = s + acc[mt][2];
    #pragma unroll
    for (int r = 0; r < 4; ++r)
      C[(size_t)(m0 + mt*16 + fg*4 + r)*N + n0 + w*16 + fr] = s[r];
  }
}

// ---------------- 2-way split-K reduce, float4 -----------------------------
__global__ __launch_bounds__(256)
void k_add2(const float* __restrict__ A, const float* __restrict__ B,
            float* __restrict__ O, int n4)
{
  int i = blockIdx.x*256 + threadIdx.x;
  if (i < n4){
    float4 a = reinterpret_cast<const float4*>(A)[i];
    float4 b = reinterpret_cast<const float4*>(B)[i];
    reinterpret_cast<float4*>(O)[i] = make_float4(a.x+b.x, a.y+b.y, a.z+b.z, a.w+b.w);
  }
}

// ---------------- Z = noise * exp(relu(LP)) + relu(MP) ---------------------
__global__ __launch_bounds__(256)
void k_z2(const float* __restrict__ MPLP, const float* __restrict__ noise,
          float* __restrict__ Z)
{
  int i = blockIdx.x*256 + threadIdx.x;
  int m = i >> 7, c = i & 127;
  float mp = fmaxf(MPLP[(size_t)m*256 + c], 0.0f);
  float lp = fmaxf(MPLP[(size_t)m*256 + 128 + c], 0.0f);
  Z[i] = noise[i]*expf(lp) + mp;
}

// ---------------- symmetric logits GEMM (f32) ------------------------------
__global__ __launch_bounds__(256)
void k_zzt(const float* __restrict__ Z, float* __restrict__ C)
{
  const int bx = blockIdx.x, by = blockIdx.y;
  if (by > bx) return;
  __shared__ float As[16][68];
  __shared__ float Bs[16][68];
  const int t = threadIdx.x, tx = t & 15, ty = t >> 4;
  const int m0 = by*64, n0 = bx*64;
  const int mA = t >> 2, kA = (t & 3) * 4;
  float acc[4][4] = {};
  for (int k0 = 0; k0 < 128; k0 += 16){
    float4 va = *reinterpret_cast<const float4*>(Z + (size_t)(m0+mA)*128 + k0 + kA);
    As[kA+0][mA]=va.x; As[kA+1][mA]=va.y; As[kA+2][mA]=va.z; As[kA+3][mA]=va.w;
    float4 vb = *reinterpret_cast<const float4*>(Z + (size_t)(n0+mA)*128 + k0 + kA);
    Bs[kA+0][mA]=vb.x; Bs[kA+1][mA]=vb.y; Bs[kA+2][mA]=vb.z; Bs[kA+3][mA]=vb.w;
    __syncthreads();
    #pragma unroll
    for (int kk = 0; kk < 16; ++kk) {
      float4 av = *reinterpret_cast<const float4*>(&As[kk][ty*4]);
      float4 bv = *reinterpret_cast<const float4*>(&Bs[kk][tx*4]);
      float a[4]={av.x,av.y,av.z,av.w};
      float b[4]={bv.x,bv.y,bv.z,bv.w};
      #pragma unroll
      for (int i=0;i<4;++i)
        #pragma unroll
        for (int j=0;j<4;++j)
          acc[i][j] = fmaf(a[i], b[j], acc[i][j]);
    }
    __syncthreads();
  }
  #pragma unroll
  for (int i=0;i<4;++i){
    float* cp = C + (size_t)(m0+ty*4+i)*NN + (n0 + tx*4);
    *reinterpret_cast<float4*>(cp) = make_float4(acc[i][0],acc[i][1],acc[i][2],acc[i][3]);
  }
  if (bx != by){
    for (int c0 = 0; c0 < 64; c0 += 16){
      __syncthreads();
      if (tx >= c0/4 && tx < c0/4 + 4){
        #pragma unroll
        for (int i=0;i<4;++i)
          #pragma unroll
          for (int j=0;j<4;++j)
            As[tx*4 + j - c0][ty*4 + i] = acc[i][j];
      }
      __syncthreads();
      const int c = t & 63, r0 = t >> 6;
      #pragma unroll
      for (int rr = 0; rr < 4; ++rr)
        C[(size_t)(n0 + c0 + r0 + rr*4)*NN + m0 + c] = As[r0 + rr*4][c];
    }
  }
}

// ---------------- M32xN64 tiled GEMM ---------------------------------------
template<typename TA>
__global__ __launch_bounds__(256)
void k_gemm32(const TA* __restrict__ A, const float* __restrict__ B,
              float* __restrict__ C, int M, int N, int K, int ldc,
              const float* __restrict__ rowscale, const float* __restrict__ bias,
              int flags)
{
  __shared__ float As[16][36];
  __shared__ float Bs[16][68];
  const int t  = threadIdx.x;
  const int tx = t & 15, ty = t >> 4;
  const int m0 = blockIdx.y * 32, n0 = blockIdx.x * 64;
  float acc[2][4] = {};
  for (int k0 = 0; k0 < K; k0 += 16) {
    if (t < 128){
      const int mA = t >> 2, kA = (t & 3) * 4;
      if constexpr (std::is_same<TA, float>::value) {
        float4 v = *reinterpret_cast<const float4*>(A + (size_t)(m0+mA)*K + (k0+kA));
        As[kA+0][mA]=v.x; As[kA+1][mA]=v.y; As[kA+2][mA]=v.z; As[kA+3][mA]=v.w;
      } else {
        int u = *reinterpret_cast<const int*>(A + (size_t)(m0+mA)*K + (k0+kA));
        As[kA+0][mA]=(float)(int)(signed char)( u       & 0xff);
        As[kA+1][mA]=(float)(int)(signed char)((u>>8)   & 0xff);
        As[kA+2][mA]=(float)(int)(signed char)((u>>16)  & 0xff);
        As[kA+3][mA]=(float)(int)(signed char)((u>>24)  & 0xff);
      }
    }
    {
      const int kB = t >> 4, nB = (t & 15) * 4;
      float4 w = *reinterpret_cast<const float4*>(B + (size_t)(k0+kB)*N + (n0+nB));
      Bs[kB][nB+0]=w.x; Bs[kB][nB+1]=w.y; Bs[kB][nB+2]=w.z; Bs[kB][nB+3]=w.w;
    }
    __syncthreads();
    #pragma unroll
    for (int kk = 0; kk < 16; ++kk) {
      float a0 = As[kk][ty*2+0];
      float a1 = As[kk][ty*2+1];
      float4 bv = *reinterpret_cast<const float4*>(&Bs[kk][tx*4]);
      float b[4]={bv.x,bv.y,bv.z,bv.w};
      #pragma unroll
      for (int j=0;j<4;++j){
        acc[0][j] = fmaf(a0, b[j], acc[0][j]);
        acc[1][j] = fmaf(a1, b[j], acc[1][j]);
      }
    }
    __syncthreads();
  }
  #pragma unroll
  for (int i=0;i<2;++i){
    const int m = m0 + ty*2 + i;
    const float rsv = (flags & F_RS) ? rowscale[m] : 1.0f;
    float* cp = C + (size_t)m*ldc + (n0 + tx*4);
    float o[4];
    #pragma unroll
    for (int j=0;j<4;++j){
      float v = acc[i][j] * rsv;
      if (flags & F_BIAS) v += bias[n0 + tx*4 + j];
      if (flags & F_ACC)  v += cp[j];
      if (flags & F_RELU) v = fmaxf(v, 0.0f);
      o[j] = v;
    }
    *reinterpret_cast<float4*>(cp) = make_float4(o[0],o[1],o[2],o[3]);
  }
}

// ---------------- M32 tiled GEMM, B transposed -----------------------------
__global__ __launch_bounds__(256)
void k_gemm32T(const float* __restrict__ A, const float* __restrict__ B,
               float* __restrict__ C, int M, int N, int K, int ldc)
{
  __shared__ float As[16][36];
  __shared__ float Bs[16][68];
  const int t  = threadIdx.x;
  const int tx = t & 15, ty = t >> 4;
  const int m0 = blockIdx.y * 32, n0 = blockIdx.x * 64;
  float acc[2][4] = {};
  for (int k0 = 0; k0 < K; k0 += 16) {
    if (t < 128){
      const int mA = t >> 2, kA = (t & 3) * 4;
      float4 v = *reinterpret_cast<const float4*>(A + (size_t)(m0+mA)*K + (k0+kA));
      As[kA+0][mA]=v.x; As[kA+1][mA]=v.y; As[kA+2][mA]=v.z; As[kA+3][mA]=v.w;
    }
    {
      const int nB = t >> 2, kB = (t & 3) * 4;
      float4 w = *reinterpret_cast<const float4*>(B + (size_t)(n0+nB)*K + (k0+kB));
      Bs[kB+0][nB]=w.x; Bs[kB+1][nB]=w.y; Bs[kB+2][nB]=w.z; Bs[kB+3][nB]=w.w;
    }
    __syncthreads();
    #pragma unroll
    for (int kk = 0; kk < 16; ++kk) {
      float a0 = As[kk][ty*2+0];
      float a1 = As[kk][ty*2+1];
      float4 bv = *reinterpret_cast<const float4*>(&Bs[kk][tx*4]);
      float b[4]={bv.x,bv.y,bv.z,bv.w};
      #pragma unroll
      for (int j=0;j<4;++j){
        acc[0][j] = fmaf(a0, b[j], acc[0][j]);
        acc[1][j] = fmaf(a1, b[j], acc[1][j]);
      }
    }
    __syncthreads();
  }
  #pragma unroll
  for (int i=0;i<2;++i){
    const int m = m0 + ty*2 + i;
    float* cp = C + (size_t)m*ldc + (n0 + tx*4);
    *reinterpret_cast<float4*>(cp) = make_float4(acc[i][0],acc[i][1],acc[i][2],acc[i][3]);
  }
}

// ---------------- fused dual GEMM ------------------------------------------
__global__ __launch_bounds__(256)
void k_fc(const float* __restrict__ A1, const float* __restrict__ B1,
          const float* __restrict__ bias,
          const float* __restrict__ A2, const float* __restrict__ B2,
          const float* __restrict__ rowscale,
          float* __restrict__ C, int N, int K1, int K2, int relu)
{
  __shared__ float As[16][36];
  __shared__ float Bs[16][68];
  const int t  = threadIdx.x;
  const int tx = t & 15, ty = t >> 4;
  const int m0 = blockIdx.y * 32, n0 = blockIdx.x * 64;
  float acc1[2][4] = {};
  float acc2[2][4] = {};
  for (int k0 = 0; k0 < K1; k0 += 16) {
    if (t < 128){
      const int mA = t >> 2, kA = (t & 3) * 4;
      float4 v = *reinterpret_cast<const float4*>(A1 + (size_t)(m0+mA)*K1 + (k0+kA));
      As[kA+0][mA]=v.x; As[kA+1][mA]=v.y; As[kA+2][mA]=v.z; As[kA+3][mA]=v.w;
    }
    {
      const int kB = t >> 4, nB = (t & 15) * 4;
      float4 w = *reinterpret_cast<const float4*>(B1 + (size_t)(k0+kB)*N + (n0+nB));
      Bs[kB][nB+0]=w.x; Bs[kB][nB+1]=w.y; Bs[kB][nB+2]=w.z; Bs[kB][nB+3]=w.w;
    }
    __syncthreads();
    #pragma unroll
    for (int kk = 0; kk < 16; ++kk) {
      float a0 = As[kk][ty*2+0];
      float a1 = As[kk][ty*2+1];
      float4 bv = *reinterpret_cast<const float4*>(&Bs[kk][tx*4]);
      float b[4]={bv.x,bv.y,bv.z,bv.w};
      #pragma unroll
      for (int j=0;j<4;++j){
        acc1[0][j] = fmaf(a0, b[j], acc1[0][j]);
        acc1[1][j] = fmaf(a1, b[j], acc1[1][j]);
      }
    }
    __syncthreads();
  }
  for (int k0 = 0; k0 < K2; k0 += 16) {
    if (t < 128){
      const int mA = t >> 2, kA = (t & 3) * 4;
      float4 v = *reinterpret_cast<const float4*>(A2 + (size_t)(m0+mA)*K2 + (k0+kA));
      As[kA+0][mA]=v.x; As[kA+1][mA]=v.y; As[kA+2][mA]=v.z; As[kA+3][mA]=v.w;
    }
    {
      const int kB = t >> 4, nB = (t & 15) * 4;
      float4 w = *reinterpret_cast<const float4*>(B2 + (size_t)(k0+kB)*N + (n0+nB));
      Bs[kB][nB+0]=w.x; Bs[kB][nB+1]=w.y; Bs[kB][nB+2]=w.z; Bs[kB][nB+3]=w.w;
    }
    __syncthreads();
    #pragma unroll
    for (int kk = 0; kk < 16; ++kk) {
      float a0 = As[kk][ty*2+0];
      float a1 = As[kk][ty*2+1];
      float4 bv = *reinterpret_cast<const float4*>(&Bs[kk][tx*4]);
      float b[4]={bv.x,bv.y,bv.z,bv.w};
      #pragma unroll
      for (int j=0;j<4;++j){
        acc2[0][j] = fmaf(a0, b[j], acc2[0][j]);
        acc2[1][j] = fmaf(a1, b[j], acc2[1][j]);
      }
    }
    __syncthreads();
  }
  #pragma unroll
  for (int i=0;i<2;++i){
    const int m = m0 + ty*2 + i;
    const float rsv = rowscale[m];
    float* cp = C + (size_t)m*N + (n0 + tx*4);
    float o[4];
    #pragma unroll
    for (int j=0;j<4;++j){
      float t1 = acc1[i][j] + bias[n0 + tx*4 + j];
      float v  = acc2[i][j] * rsv;
      v += t1;
      if (relu) v = fmaxf(v, 0.0f);
      o[j] = v;
    }
    *reinterpret_cast<float4*>(cp) = make_float4(o[0],o[1],o[2],o[3]);
  }
}

// ---------------- weight concat --------------------------------------------
__global__ __launch_bounds__(256)
void k_wcat(const float* __restrict__ Wm, const float* __restrict__ Wl,
            float* __restrict__ Wcat)
{
  int idx = blockIdx.x*256 + threadIdx.x;
  int row = idx >> 8, col = idx & 255;
  Wcat[idx] = (col < 128) ? Wm[row*128 + col] : Wl[row*128 + (col - 128)];
}

// ---------------- per-row compact-gather SpMM ------------------------------
template<int D>
__global__ __launch_bounds__(256)
void k_spmmF(const float* __restrict__ A, const float* __restrict__ B,
             float* __restrict__ C)
{
  const int row = blockIdx.x, t = threadIdx.x;
  const int lane = t & 63, wv = t >> 6;
  __shared__ int   sc[288];
  __shared__ float sv[288];
  __shared__ int wtot[4];
  __shared__ int nsh;
  const float4* r4 = reinterpret_cast<const float4*>(A + (size_t)row*NN) + t*4;
  float lv[16];
  #pragma unroll
  for (int q=0;q<4;++q){
    float4 v = r4[q];
    lv[q*4+0]=v.x; lv[q*4+1]=v.y; lv[q*4+2]=v.z; lv[q*4+3]=v.w;
  }
  int c = 0;
  #pragma unroll
  for (int k=0;k<16;++k) c += (lv[k] != 0.0f);
  int inc = c;
  #pragma unroll
  for (int off=1; off<64; off<<=1){
    int v = __shfl_up(inc, off, 64);
    if (lane >= off) inc += v;
  }
  if (lane == 63) wtot[wv] = inc;
  __syncthreads();
  int wbase = 0;
  #pragma unroll
  for (int ww=0; ww<3; ++ww) if (ww < wv) wbase += wtot[ww];
  int pos = wbase + inc - c;
  #pragma unroll
  for (int k=0;k<16;++k){
    if (lv[k] != 0.0f){
      if (pos >= 0 && pos < 288){ sc[pos] = t*16+k; sv[pos] = lv[k]; }
      pos++;
    }
  }
  if (t == 255){
    int tot = wbase + inc;
    nsh = (tot < 288) ? tot : 288;
  }
  __syncthreads();
  const int n = nsh;
  float acc = 0.f;
  int s = 0;
  for (; s+4 <= n; s += 4){
    float x0 = B[(size_t)sc[s+0]*D + t];
    float x1 = B[(size_t)sc[s+1]*D + t];
    float x2 = B[(size_t)sc[s+2]*D + t];
    float x3 = B[(size_t)sc[s+3]*D + t];
    acc = fmaf(sv[s+0], x0, acc);
    acc = fmaf(sv[s+1], x1, acc);
    acc = fmaf(sv[s+2], x2, acc);
    acc = fmaf(sv[s+3], x3, acc);
  }
  for (; s < n; ++s) acc = fmaf(sv[s], B[(size_t)sc[s]*D + t], acc);
  C[(size_t)row*D + t] = acc;
}

// ---------------- selection -------------------------------------------------
__global__ __launch_bounds__(256)
void k_initstats(SelParams* p)
{
  int t = threadIdx.x;
  if (t == 0){
    p->min_ord = 0xFFFFFFFFu; p->max_ord = 0u; p->n_up = 0u;
    p->rm_prefix = 0u; p->add_prefix = 0u;
  }
  p->hist_rm[t] = 0u; p->hist_add[t] = 0u;
}

__global__ __launch_bounds__(256)
void k_stats1(const float* __restrict__ L, const float* __restrict__ adj,
              unsigned long long* __restrict__ mask, SelParams* __restrict__ p)
{
  unsigned mn=0xFFFFFFFFu, mx=0u, cnt=0u;
  size_t g = (size_t)blockIdx.x*256 + threadIdx.x;
  const size_t stride = (size_t)gridDim.x*256;
  for (; g < 262144; g += stride){
    const int i  = (int)(g >> 6);
    const int jb = (int)(g & 63) << 6;
    unsigned long long m = 0ull;
    if (jb + 63 > i){
      const float4* a4 = reinterpret_cast<const float4*>(adj + (size_t)i*NN + jb);
      const float4* l4 = reinterpret_cast<const float4*>(L   + (size_t)i*NN + jb);
      for (int w = 0; w < 16; ++w){
        const int j0 = jb + w*4;
        if (j0 + 3 <= i) continue;
        float4 av = a4[w]; float4 lv = l4[w];
        float ae[4]={av.x,av.y,av.z,av.w};
        float le[4]={lv.x,lv.y,lv.z,lv.w};
        #pragma unroll
        for (int e=0;e<4;++e){
          const int jj = j0 + e;
          if (jj > i){
            if (ae[e] != 0.0f){ m |= 1ull << (jj & 63); cnt++; }
            unsigned o = ordenc(le[e]);
            mn = (o < mn) ? o : mn;
            mx = (o > mx) ? o : mx;
          }
        }
      }
    }
    mask[g] = m;
  }
  __shared__ unsigned smn[256], smx[256], sc[256];
  int t = threadIdx.x;
  smn[t]=mn; smx[t]=mx; sc[t]=cnt; __syncthreads();
  for (int s=128; s>0; s>>=1){
    if (t < s){
      smn[t] = (smn[t+s] < smn[t]) ? smn[t+s] : smn[t];
      smx[t] = (smx[t+s] > smx[t]) ? smx[t+s] : smx[t];
      sc[t] += sc[t+s];
    }
    __syncthreads();
  }
  if (t == 0){
    atomicMin(&p->min_ord, smn[0]);
    atomicMax(&p->max_ord, smx[0]);
    atomicAdd(&p->n_up, sc[0]);
  }
}

__global__ void k_stats2(SelParams* p)
{
  float mnv = orddec_ok(p->min_ord), mxv = orddec_ok(p->max_ord);
  float lo = fminf(mnv, 0.0f), hi = fmaxf(mxv, 0.0f);
  p->lo = lo;
  p->M  = hi - lo;
  p->c0 = (0.0f - lo) / p->M;
  p->n_change = p->n_up;
}

__global__ __launch_bounds__(256)
void k_hist2(const float* __restrict__ L, const unsigned long long* __restrict__ mask,
             SelParams* __restrict__ p, int shift)
{
  __shared__ unsigned hr[256], ha[256];
  const int t = threadIdx.x;
  hr[t]=0u; ha[t]=0u; __syncthreads();
  const float lo = p->lo, Mv = p->M;
  const unsigned pr = p->rm_prefix, pa = p->add_prefix;
  const float4* L4 = reinterpret_cast<const float4*>(L);
  size_t q = (size_t)blockIdx.x*256 + t;
  const size_t stride = (size_t)gridDim.x*256;
  for (; q < TTOT/4; q += stride){
    const int i = (int)(q >> 10);
    const int j = (int)(q & 1023) << 2;
    if (j + 3 <= i) continue;
    float4 l = L4[q];
    const unsigned long long w = mask[q >> 4];
    float le[4]={l.x,l.y,l.z,l.w};
    #pragma unroll
    for (int e=0;e<4;++e){
      const int jj = j + e;
      if (jj <= i) continue;
      const unsigned key = __float_as_uint((le[e] - lo) / Mv);
      if (key == 0u) continue;
      const bool edge = (w >> (jj & 63)) & 1ull;
      if (edge){
        if (shift == 24 || (key >> (shift+8)) == pr) atomicAdd(&hr[(key>>shift)&255u], 1u);
      } else {
        if (shift == 24 || (key >> (shift+8)) == pa) atomicAdd(&ha[(key>>shift)&255u], 1u);
      }
    }
  }
  __syncthreads();
  if (hr[t]) atomicAdd(&p->hist_rm[t], hr[t]);
  if (ha[t]) atomicAdd(&p->hist_add[t], ha[t]);
}

__global__ __launch_bounds__(256)
void k_scan2(SelParams* __restrict__ p, int shift)
{
  const int t = threadIdx.x;
  if (t == 0){
    const unsigned c0k  = __float_as_uint(p->c0);
    const unsigned n_up = p->n_up;
    {
      unsigned injb = 300u, inj = 0u;
      if (c0k != 0u && (shift == 24 || (c0k >> (shift+8)) == p->rm_prefix)){
        injb = (c0k >> shift) & 255u; inj = n_up;
      }
      unsigned k;
      if (shift == 24){
        unsigned tot = inj;
        for (int d=0; d<256; ++d) tot += p->hist_rm[d];
        k = (tot < p->n_change) ? tot : p->n_change;
      } else k = p->rm_k;
      unsigned cum = 0u, digit = 255u;
      for (int d=0; d<256; ++d){
        unsigned hd = p->hist_rm[d] + (((unsigned)d == injb) ? inj : 0u);
        if (cum + hd >= k){ digit = (unsigned)d; k -= cum; break; }
        cum += hd;
      }
      p->rm_prefix = (p->rm_prefix << 8) | digit;
      p->rm_k = k;
      if (shift == 0) p->t_rm = __uint_as_float(p->rm_prefix);
    }
    {
      unsigned injb = 300u, inj = 0u;
      if (c0k != 0u && (shift == 24 || (c0k >> (shift+8)) == p->add_prefix)){
        injb = (c0k >> shift) & 255u;
        inj  = 8386560u - n_up + 4096u;
      }
      unsigned k;
      if (shift == 24){
        unsigned tot = inj;
        for (int d=0; d<256; ++d) tot += p->hist_add[d];
        k = (tot < p->n_change) ? tot : p->n_change;
      } else k = p->add_k;
      unsigned cum = 0u, digit = 0u;
      for (int d=255; d>=0; --d){
        unsigned hd = p->hist_add[d] + (((unsigned)d == injb) ? inj : 0u);
        if (cum + hd >= k){ digit = (unsigned)d; k -= cum; break; }
        cum += hd;
      }
      p->add_prefix = (p->add_prefix << 8) | digit;
      p->add_k = k;
      if (shift == 0) p->t_add = __uint_as_float(p->add_prefix);
    }
  }
  __syncthreads();
  p->hist_rm[t] = 0u; p->hist_add[t] = 0u;
}

// ---------------- build adj_new ---------------------------------------------
__device__ __forceinline__ int adjval(bool edge, float v, float c0v, float trm, float tad)
{
  int rmU = (edge && v   >  0.0f && v   <= trm) ? 1 : 0;
  int rmL = (edge && c0v >  0.0f && c0v <= trm) ? 1 : 0;
  int adU = (!edge && v   >= tad) ? 1 : 0;
  int adL = (!edge && c0v >= tad) ? 1 : 0;
  return (edge ? 1 : 0) - rmU - rmL + adU + adL;
}

__global__ __launch_bounds__(256)
void k_apply(const float* __restrict__ L, const unsigned long long* __restrict__ mask,
             const SelParams* __restrict__ p, signed char* __restrict__ A8)
{
  const int bx = blockIdx.x, by = blockIdx.y;
  if (by > bx) return;
  const float lo=p->lo, Mv=p->M, c0v=p->c0, trm=p->t_rm, tad=p->t_add;
  const int i0 = by*64, j0 = bx*64, t = threadIdx.x;
  __shared__ signed char Vs[64][65];
  if (bx == by){
    for (int it=0; it<16; ++it){
      int e = it*256 + t; int r = e>>6, c = e&63;
      size_t idx = (size_t)(i0+r)*NN + (j0+c);
      if (r < c){
        bool edge = (mask[idx>>6] >> ((j0+c) & 63)) & 1ull;
        float v = (L[idx] - lo) / Mv;
        int val = adjval(edge, v, c0v, trm, tad);
        A8[idx] = (signed char)val;
        Vs[c][r] = (signed char)val;
      } else if (r == c){
        A8[idx] = 1;
      }
    }
    __syncthreads();
    for (int it=0; it<16; ++it){
      int e = it*256 + t; int r = e>>6, c = e&63;
      if (r > c) A8[(size_t)(i0+r)*NN + (j0+c)] = Vs[r][c];
    }
  } else {
    for (int it=0; it<16; ++it){
      int e = it*256 + t; int r = e>>6, c = e&63;
      size_t idx = (size_t)(i0+r)*NN + (j0+c);
      bool edge = (mask[idx>>6] >> ((j0+c) & 63)) & 1ull;
      float v = (L[idx] - lo) / Mv;
      int val = adjval(edge, v, c0v, trm, tad);
      A8[idx] = (signed char)val;
      Vs[c][r] = (signed char)val;
    }
    __syncthreads();
    for (int it=0; it<16; ++it){
      int e = it*256 + t; int r = e>>6, c = e&63;
      A8[(size_t)(j0+r)*NN + (i0+c)] = Vs[r][c];
    }
  }
}

// ---------------- per-row scale for mean_neigh ------------------------------
__global__ __launch_bounds__(256)
void k_rowsum8(const signed char* __restrict__ A8, float* __restrict__ s_mean)
{
  const int row = blockIdx.x, t = threadIdx.x;
  const int4 w = reinterpret_cast<const int4*>(A8 + (size_t)row*NN)[t];
  int s = 0, a = 0;
  int vs[4] = {w.x, w.y, w.z, w.w};
  #pragma unroll
  for (int q=0; q<4; ++q){
    int u = vs[q];
    #pragma unroll
    for (int b=0; b<4; ++b){
      int c = (int)(signed char)((u >> (8*b)) & 0xff);
      s += c; a += (c < 0) ? -c : c;
    }
  }
  __shared__ int rs_[256], ra_[256];
  rs_[t]=s; ra_[t]=a; __syncthreads();
  for (int st=128; st>0; st>>=1){
    if (t < st){ rs_[t]+=rs_[t+st]; ra_[t]+=ra_[t+st]; }
    __syncthreads();
  }
  if (t == 0){
    float rs = (float)rs_[0], ra = (float)ra_[0];
    float A = fmaxf(ra, 1e-12f);
    s_mean[row] = (1.0f / A) / (rs / A + 1e-7f);
  }
}

// ---------------- row log_softmax (512 cols, in place) ----------------------
__global__ __launch_bounds__(256)
void k_lsm(float* __restrict__ X)
{
  const int row = blockIdx.x, t = threadIdx.x;
  float* x = X + (size_t)row*512;
  float v0 = x[t], v1 = x[t+256];
  __shared__ float red[256];
  red[t] = fmaxf(v0, v1); __syncthreads();
  for (int s=128; s>0; s>>=1){
    if (t < s) red[t] = fmaxf(red[t], red[t+s]);
    __syncthreads();
  }
  float m = red[0]; __syncthreads();
  red[t] = expf(v0-m) + expf(v1-m); __syncthreads();
  for (int s=128; s>0; s>>=1){
    if (t < s) red[t] += red[t+s];
    __syncthreads();
  }
  float ls = logf(red[0]);
  x[t]     = (v0 - m) - ls;
  x[t+256] = (v1 - m) - ls;
}

// ---------------- driver ---------------------------------------------------
extern "C" void kernel_launch(void* const* d_in, const int* in_sizes, int n_in,
                              void* d_out, int out_size, void* d_ws, size_t ws_size,
                              hipStream_t stream)
{
  (void)in_sizes; (void)n_in; (void)out_size; (void)ws_size;
  const float* adj_norm = (const float*)d_in[0];
  const float* adj_ori  = (const float*)d_in[1];
  const float* feats    = (const float*)d_in[2];
  const float* img      = (const float*)d_in[3];
  const float* csd_img  = (const float*)d_in[5];
  const float* noise    = (const float*)d_in[6];
  const float* Wb       = (const float*)d_in[7];
  const float* Wm       = (const float*)d_in[8];
  const float* Wl       = (const float*)d_in[9];
  const float* fc1W     = (const float*)d_in[10];
  const float* fc1b     = (const float*)d_in[11];
  const float* fc2W     = (const float*)d_in[12];
  const float* fc2b     = (const float*)d_in[13];

  float* out    = (float*)d_out;
  float* out_pt = out;                 // preds_total 4096x64
  float* out_ft = out + 262144;        // feat_total  4096x512 (free until fc2)
  float* out_pi = out + 2359296;       // preds_img   4096x64
  float* out_lg = out + 2621440;       // adj_logits  4096x4096

  char* W = (char*)d_ws;
  signed char* adj8 = (signed char*)W;                              // 16MB
  float* bufA   = (float*)(W + (16u<<20));                          // 8MB
  float* bufB   = (float*)(W + (24u<<20));                          // 4MB
  float* HMHL   = (float*)(W + (28u<<20));                          // 4MB
  float* MPLP   = (float*)(W + (32u<<20));                          // 4MB
  float* Z      = (float*)(W + (36u<<20));                          // 2MB
  unsigned long long* mask = (unsigned long long*)(W + (38u<<20));  // 2MB
  float* p2q0   = (float*)(W + (40u<<20));                          // 4MB
  float* s_mean = (float*)(W + (44u<<20));                          // 16KB
  SelParams* sp = (SelParams*)(W + (44u<<20) + 65536);
  float* Wcat   = (float*)(W + (45u<<20));                          // 256KB
  // B bf16 plane regions (dead buffers after apply):
  ushort_t* BT1h = (ushort_t*)(W + (28u<<20));   // 4MB
  ushort_t* BT1m = (ushort_t*)(W + (32u<<20));   // 4MB
  ushort_t* BT1l = (ushort_t*)(W + (36u<<20));   // 4MB (Z+mask region, dead after apply)
  ushort_t* BT2h = (ushort_t*)(W + (28u<<20));   // 2MB
  ushort_t* BT2m = (ushort_t*)(W + (30u<<20));   // 2MB
  ushort_t* BT2l = (ushort_t*)(W + (32u<<20));   // 2MB

  dim3 B(256);
  auto G32 = [](int M, int N){ return dim3((unsigned)(N/64), (unsigned)(M/32)); };

  // ---- ep_net ----
  k_gemm32<float><<<G32(4096,256),B,0,stream>>>(img, Wb, bufA, 4096,256,512,256, nullptr,nullptr,0);  // T1
  k_spmmF<256><<<4096,B,0,stream>>>(adj_norm, bufA, bufB);                                            // hidden
  k_wcat<<<256,B,0,stream>>>(Wm, Wl, Wcat);
  k_gemm32<float><<<G32(4096,256),B,0,stream>>>(bufB, Wcat, HMHL, 4096,256,256,256, nullptr,nullptr,0); // [HM|HL]
  k_spmmF<256><<<4096,B,0,stream>>>(adj_norm, HMHL, MPLP);                                            // [MP|LP]
  k_z2<<<2048,B,0,stream>>>(MPLP, noise, Z);
  k_zzt<<<dim3(64,64),B,0,stream>>>(Z, out_lg);                                                       // logits (f32)

  // ---- edge rewiring ----
  k_initstats<<<1,B,0,stream>>>(sp);
  k_stats1<<<1024,B,0,stream>>>(out_lg, adj_ori, mask, sp);
  k_stats2<<<1,1,0,stream>>>(sp);
  for (int shift = 24; shift >= 0; shift -= 8){
    k_hist2<<<2048,B,0,stream>>>(out_lg, mask, sp, shift);
    k_scan2<<<1,B,0,stream>>>(sp, shift);
  }
  k_apply<<<dim3(64,64),B,0,stream>>>(out_lg, mask, sp, adj8);

  // ---- row scales ----
  k_rowsum8<<<4096,B,0,stream>>>(adj8, s_mean);

  // ---- nc_net (MFMA split-K=2, transposed wave mapping) ----
  k_b3t<512><<<dim3(8,64),B,0,stream>>>(feats, BT1h, BT1m, BT1l);
  k_mfma<<<dim3(8,64,2),B,0,stream>>>(adj8, BT1h, BT1m, BT1l, bufA, out_ft, 512); // P halves
  k_add2<<<2048,B,0,stream>>>(bufA, out_ft, bufA, 524288);                        // P
  k_fc<<<G32(4096,256),B,0,stream>>>(feats, fc1W, fc1b, bufA, fc1W + 512*256, s_mean,
                                     bufB, 256, 512, 512, 1);                     // h1
  k_b3t<256><<<dim3(4,64),B,0,stream>>>(bufB, BT2h, BT2m, BT2l);
  k_mfma<<<dim3(4,64,2),B,0,stream>>>(adj8, BT2h, BT2m, BT2l, p2q0, out_ft, 256); // P2 halves
  k_add2<<<1024,B,0,stream>>>(p2q0, out_ft, bufA, 262144);                        // P2
  k_fc<<<G32(4096,512),B,0,stream>>>(bufB, fc2W, fc2b, bufA, fc2W + 256*512, s_mean,
                                     out_ft, 512, 256, 256, 0);
  k_lsm<<<4096,B,0,stream>>>(out_ft);

  // ---- heads ----
  k_gemm32T<<<G32(4096,64),B,0,stream>>>(out_ft, csd_img, out_pt, 4096,64,512,64);
  k_gemm32T<<<G32(4096,64),B,0,stream>>>(img, csd_img, out_pi, 4096,64,512,64);
}